// Round 2
// baseline (1311.016 us; speedup 1.0000x reference)
//
#include <hip/hip_runtime.h>
#include <stdint.h>

// ---------------- constants ----------------
#define Bb 2
#define Tt 2048
#define Cc 1024
#define Hh 16
#define HD 64
#define Mm (Bb*Tt)   // 4096

typedef __bf16 bf16x8 __attribute__((ext_vector_type(8)));
typedef float  f32x4  __attribute__((ext_vector_type(4)));

#define DEV static __device__ __forceinline__

DEV float asfloat_(uint32_t u){ union{uint32_t u; float f;} x; x.u=u; return x.f; }
DEV uint32_t asuint_(float f){ union{float f; uint32_t u;} x; x.f=f; return x.u; }
DEV float bflo(uint32_t p){ return asfloat_(p<<16); }
DEV float bfhi(uint32_t p){ return asfloat_(p & 0xffff0000u); }
DEV unsigned short f2bf(float f){
  uint32_t u = asuint_(f);
  uint32_t r = (u + 0x7fffu + ((u>>16)&1u)) >> 16;
  return (unsigned short)r;
}
DEV float gelu_(float x){
  float x3 = x*x*x;
  float t  = 0.7978845608028654f * (x + 0.044715f*x3);
  float e  = __expf(2.0f*t);
  float th = 1.0f - 2.0f/(e + 1.0f);   // tanh(t), inf-safe
  return 0.5f * x * (1.0f + th);
}

// ---------------- weight fp32 [K][N] -> bf16 W^T [N][K] ----------------
__global__ void wcvt_kernel(const float* __restrict__ W, unsigned short* __restrict__ WT,
                            int K, int N) {
  __shared__ float tile[32][33];
  int tx = threadIdx.x & 31, ty = threadIdx.x >> 5;       // 32 x 8
  int kb = blockIdx.x * 32, nb = blockIdx.y * 32;
  #pragma unroll
  for (int r = 0; r < 32; r += 8)
    tile[ty + r][tx] = W[(size_t)(kb + ty + r) * N + nb + tx];
  __syncthreads();
  #pragma unroll
  for (int r = 0; r < 32; r += 8)
    WT[(size_t)(nb + ty + r) * K + kb + tx] = f2bf(tile[tx][ty + r]);
}

// ---------------- layernorm fp32 -> bf16 ----------------
__global__ void ln_kernel(const float* __restrict__ X, const float* __restrict__ g,
                          const float* __restrict__ bb, unsigned short* __restrict__ O) {
  int row = blockIdx.x, t = threadIdx.x;
  const float4* xr = (const float4*)(X + (size_t)row * Cc);
  float4 v = xr[t];
  float s = v.x + v.y + v.z + v.w;
  float q = v.x*v.x + v.y*v.y + v.z*v.z + v.w*v.w;
  #pragma unroll
  for (int o = 32; o > 0; o >>= 1) { s += __shfl_xor(s, o); q += __shfl_xor(q, o); }
  __shared__ float ss[4], sq[4];
  int w = t >> 6;
  if ((t & 63) == 0) { ss[w] = s; sq[w] = q; }
  __syncthreads();
  s = ss[0] + ss[1] + ss[2] + ss[3];
  q = sq[0] + sq[1] + sq[2] + sq[3];
  float mu  = s * (1.0f/Cc);
  float var = q * (1.0f/Cc) - mu*mu;
  float rstd = rsqrtf(var + 1e-5f);
  float4 gv = ((const float4*)g)[t], bv = ((const float4*)bb)[t];
  ushort4 o4;
  o4.x = f2bf((v.x-mu)*rstd*gv.x + bv.x);
  o4.y = f2bf((v.y-mu)*rstd*gv.y + bv.y);
  o4.z = f2bf((v.z-mu)*rstd*gv.z + bv.z);
  o4.w = f2bf((v.w-mu)*rstd*gv.w + bv.w);
  ((ushort4*)(O + (size_t)row * Cc))[t] = o4;
}

// ---------------- GEMM: C = A[M][K]bf16 * (BT[N][K]bf16)^T + bias, fused epilogue -------
// MODE 0: +bias -> bf16 out        (qkv)
// MODE 1: +bias +res(f32) -> f32   (out-proj + x)
// MODE 2: +bias, gelu -> bf16      (fc1)
// MODE 3: +bias +res(f32) -> f32   (fc2 + temp)
template<int MODE>
__launch_bounds__(256, 2)
__global__ void gemm_kernel(const unsigned short* __restrict__ A,
                            const unsigned short* __restrict__ BT,
                            const float* __restrict__ bias,
                            const float* __restrict__ res,
                            void* __restrict__ Cout,
                            int N, int K) {
  __shared__ unsigned short As[128*32];
  __shared__ unsigned short Bs[128*32];
  int tid  = threadIdx.x;
  int lane = tid & 63, w = tid >> 6;
  int wr = w >> 1, wc = w & 1;
  int bm = blockIdx.x, bn = blockIdx.y;

  f32x4 acc[4][4];
  #pragma unroll
  for (int m = 0; m < 4; ++m)
    #pragma unroll
    for (int n = 0; n < 4; ++n) acc[m][n] = (f32x4){0.f,0.f,0.f,0.f};

  int arow   = tid >> 2;           // 0..63
  int kchunk = (tid & 3) * 8;      // bf16 elems within BK
  const unsigned short* Ag = A  + (size_t)(bm*128 + arow) * K + kchunk;
  const unsigned short* Bg = BT + (size_t)(bn*128 + arow) * K + kchunk;
  int nk = K >> 5;

  for (int kt = 0; kt < nk; ++kt) {
    if (kt) __syncthreads();
    const unsigned short* ag = Ag + kt*32;
    const unsigned short* bg = Bg + kt*32;
    __builtin_amdgcn_global_load_lds((const __attribute__((address_space(1))) void*)ag,
        (__attribute__((address_space(3))) void*)(As + w*512), 16, 0, 0);
    __builtin_amdgcn_global_load_lds((const __attribute__((address_space(1))) void*)(ag + (size_t)64*K),
        (__attribute__((address_space(3))) void*)(As + 2048 + w*512), 16, 0, 0);
    __builtin_amdgcn_global_load_lds((const __attribute__((address_space(1))) void*)bg,
        (__attribute__((address_space(3))) void*)(Bs + w*512), 16, 0, 0);
    __builtin_amdgcn_global_load_lds((const __attribute__((address_space(1))) void*)(bg + (size_t)64*K),
        (__attribute__((address_space(3))) void*)(Bs + 2048 + w*512), 16, 0, 0);
    __syncthreads();

    bf16x8 af[4], bfr[4];
    #pragma unroll
    for (int m = 0; m < 4; ++m)
      af[m] = *(const bf16x8*)(As + (wr*64 + m*16 + (lane&15))*32 + (lane>>4)*8);
    #pragma unroll
    for (int n = 0; n < 4; ++n)
      bfr[n] = *(const bf16x8*)(Bs + (wc*64 + n*16 + (lane&15))*32 + (lane>>4)*8);
    #pragma unroll
    for (int m = 0; m < 4; ++m)
      #pragma unroll
      for (int n = 0; n < 4; ++n)
        acc[m][n] = __builtin_amdgcn_mfma_f32_16x16x32_bf16(af[m], bfr[n], acc[m][n], 0, 0, 0);
  }

  int r0 = bm*128 + wr*64;
  int c0 = bn*128 + wc*64;
  int lr = (lane >> 4) * 4;
  int lc = lane & 15;
  #pragma unroll
  for (int m = 0; m < 4; ++m) {
    #pragma unroll
    for (int n = 0; n < 4; ++n) {
      int col = c0 + n*16 + lc;
      float bv = bias[col];
      #pragma unroll
      for (int i = 0; i < 4; ++i) {
        int row = r0 + m*16 + lr + i;
        float v = acc[m][n][i] + bv;
        if (MODE == 1 || MODE == 3) v += res[(size_t)row * N + col];
        if (MODE == 2) v = gelu_(v);
        if (MODE == 0 || MODE == 2)
          ((unsigned short*)Cout)[(size_t)row * N + col] = f2bf(v);
        else
          ((float*)Cout)[(size_t)row * N + col] = v;
      }
    }
  }
}

// ---------------- causal attention, flash-style ----------------
// qkv bf16 [B*T][3C] rows = [q|k|v]; out att bf16 [B*T][C] at [:, h*64+d]
// block: 8 waves, wave w handles q-row q0+w; lane j = key j within 64-key tile.
__launch_bounds__(512, 1)
__global__ void attn_kernel(const unsigned short* __restrict__ qkv,
                            unsigned short* __restrict__ att) {
  __shared__ unsigned short Ks[64*68];
  __shared__ unsigned short Vs[64*68];
  int tid = threadIdx.x;
  int lane = tid & 63, w = tid >> 6;
  int bh = blockIdx.x;            // 0..31
  int b = bh >> 4, h = bh & 15;
  int q0 = blockIdx.y * 8;
  int qrow = q0 + w;

  // load my q-row (wave-uniform, broadcast loads), keep packed bf16 pairs
  uint32_t qpk[32];
  const uint32_t* qg = (const uint32_t*)(qkv + (size_t)(b*Tt + qrow)*3072 + h*64);
  #pragma unroll
  for (int i = 0; i < 32; ++i) qpk[i] = qg[i];

  float u[64];
  #pragma unroll
  for (int d = 0; d < 64; ++d) u[d] = 0.f;
  float mrun = -1e30f, lrun = 0.f;

  int nt = (q0 + 8 + 63) >> 6;
  int srow = tid >> 3;            // 0..63
  int sd   = (tid & 7) * 8;

  for (int t0 = 0; t0 < nt; ++t0) {
    __syncthreads();
    {   // stage K,V tile (bf16) into padded LDS
      size_t base = (size_t)(b*Tt + t0*64 + srow) * 3072 + h*64 + sd;
      int4 kv = *(const int4*)(qkv + base + 1024);
      int4 vv = *(const int4*)(qkv + base + 2048);
      int2 a; a.x = kv.x; a.y = kv.y;
      int2 c; c.x = kv.z; c.y = kv.w;
      *(int2*)(Ks + srow*68 + sd)     = a;
      *(int2*)(Ks + srow*68 + sd + 4) = c;
      a.x = vv.x; a.y = vv.y; c.x = vv.z; c.y = vv.w;
      *(int2*)(Vs + srow*68 + sd)     = a;
      *(int2*)(Vs + srow*68 + sd + 4) = c;
    }
    __syncthreads();

    int kidx = t0*64 + lane;
    float s = 0.f;
    const uint32_t* krow = (const uint32_t*)(Ks + lane*68);
    #pragma unroll
    for (int i = 0; i < 32; ++i) {
      uint32_t kk = krow[i];
      s += bflo(qpk[i])*bflo(kk) + bfhi(qpk[i])*bfhi(kk);
    }
    s *= 0.125f;                            // 1/sqrt(64)
    bool valid = (kidx <= qrow);
    if (!valid) s = -1e30f;

    float tmax = s;
    #pragma unroll
    for (int o = 32; o > 0; o >>= 1) tmax = fmaxf(tmax, __shfl_xor(tmax, o));
    float mnew = fmaxf(mrun, tmax);
    float corr = __expf(mrun - mnew);
    float p = valid ? __expf(s - mnew) : 0.f;
    float psum = p;
    #pragma unroll
    for (int o = 32; o > 0; o >>= 1) psum += __shfl_xor(psum, o);
    lrun = lrun * corr + psum;
    mrun = mnew;

    const uint32_t* vrow = (const uint32_t*)(Vs + lane*68);
    #pragma unroll
    for (int i = 0; i < 32; ++i) {
      uint32_t vv2 = vrow[i];
      u[2*i]   = u[2*i]  *corr + p*bflo(vv2);
      u[2*i+1] = u[2*i+1]*corr + p*bfhi(vv2);
    }
  }

  // butterfly transpose-reduce: after this, u[0] on lane l = sum_j u_j[d=l]
  #pragma unroll
  for (int k = 5; k >= 0; --k) {
    int half = 1 << k;
    bool hib = (lane >> k) & 1;
    #pragma unroll
    for (int i = 0; i < half; ++i) {
      float keep = hib ? u[i+half] : u[i];
      float send = hib ? u[i] : u[i+half];
      float recv = __shfl_xor(send, half);
      u[i] = keep + recv;
    }
  }
  float o = u[0] / lrun;
  att[(size_t)(b*Tt + qrow)*Cc + h*64 + lane] = f2bf(o);
}

// ---------------- launch ----------------
extern "C" void kernel_launch(void* const* d_in, const int* in_sizes, int n_in,
                              void* d_out, int out_size, void* d_ws, size_t ws_size,
                              hipStream_t stream) {
  const float* x    = (const float*)d_in[0];
  const float* ln1g = (const float*)d_in[1];
  const float* ln1b = (const float*)d_in[2];
  const float* Wqkv = (const float*)d_in[3];
  const float* bqkv = (const float*)d_in[4];
  const float* Wout = (const float*)d_in[5];
  const float* bout = (const float*)d_in[6];
  const float* ln2g = (const float*)d_in[7];
  const float* ln2b = (const float*)d_in[8];
  const float* Wfc1 = (const float*)d_in[9];
  const float* bfc1 = (const float*)d_in[10];
  const float* Wfc2 = (const float*)d_in[11];
  const float* bfc2 = (const float*)d_in[12];

  char* ws = (char*)d_ws;
  unsigned short* wqkvT = (unsigned short*)(ws);                 // 6 MB  [3072][1024]
  unsigned short* woutT = (unsigned short*)(ws + (6u<<20));      // 2 MB  [1024][1024]
  unsigned short* wfc1T = (unsigned short*)(ws + (8u<<20));      // 8 MB  [4096][1024]
  unsigned short* wfc2T = (unsigned short*)(ws + (16u<<20));     // 8 MB  [1024][4096]
  float*          temp  = (float*)(ws + (24u<<20));              // 16 MB [4096][1024]
  unsigned short* hbuf  = (unsigned short*)(ws + (40u<<20));     // 8 MB  [4096][1024]
  unsigned short* qkvb  = (unsigned short*)(ws + (48u<<20));     // 24 MB [4096][3072]
  unsigned short* attb  = (unsigned short*)(ws + (72u<<20));     // 8 MB  [4096][1024]
  unsigned short* a1b   = (unsigned short*)(ws + (48u<<20));     // 32 MB (reuses qkv+att, dead by fc1)

  dim3 b256(256);
  // weights -> bf16 transposed
  wcvt_kernel<<<dim3(1024/32, 3072/32), b256, 0, stream>>>(Wqkv, wqkvT, 1024, 3072);
  wcvt_kernel<<<dim3(1024/32, 1024/32), b256, 0, stream>>>(Wout, woutT, 1024, 1024);
  wcvt_kernel<<<dim3(1024/32, 4096/32), b256, 0, stream>>>(Wfc1, wfc1T, 1024, 4096);
  wcvt_kernel<<<dim3(4096/32, 1024/32), b256, 0, stream>>>(Wfc2, wfc2T, 4096, 1024);

  ln_kernel<<<Mm, b256, 0, stream>>>(x, ln1g, ln1b, hbuf);
  gemm_kernel<0><<<dim3(Mm/128, 3072/128), b256, 0, stream>>>(hbuf, wqkvT, bqkv, nullptr, qkvb, 3072, 1024);
  attn_kernel<<<dim3(Bb*Hh, Tt/8), 512, 0, stream>>>(qkvb, attb);
  gemm_kernel<1><<<dim3(Mm/128, 1024/128), b256, 0, stream>>>(attb, woutT, bout, x, temp, 1024, 1024);
  ln_kernel<<<Mm, b256, 0, stream>>>(temp, ln2g, ln2b, hbuf);
  gemm_kernel<2><<<dim3(Mm/128, 4096/128), b256, 0, stream>>>(hbuf, wfc1T, bfc1, nullptr, a1b, 4096, 1024);
  gemm_kernel<3><<<dim3(Mm/128, 1024/128), b256, 0, stream>>>(a1b, wfc2T, bfc2, temp, d_out, 1024, 4096);
}

// Round 3
// 375.278 us; speedup vs baseline: 3.4935x; 3.4935x over previous
//
#include <hip/hip_runtime.h>
#include <stdint.h>

// ---------------- constants ----------------
#define Bb 2
#define Tt 2048
#define Cc 1024
#define Hh 16
#define HD 64
#define Mm (Bb*Tt)   // 4096

typedef __bf16 bf16x8 __attribute__((ext_vector_type(8)));
typedef float  f32x4  __attribute__((ext_vector_type(4)));

#define DEV static __device__ __forceinline__

DEV float asfloat_(uint32_t u){ union{uint32_t u; float f;} x; x.u=u; return x.f; }
DEV uint32_t asuint_(float f){ union{float f; uint32_t u;} x; x.f=f; return x.u; }
DEV unsigned short f2bf(float f){
  uint32_t u = asuint_(f);
  uint32_t r = (u + 0x7fffu + ((u>>16)&1u)) >> 16;
  return (unsigned short)r;
}
DEV float gelu_(float x){
  float x3 = x*x*x;
  float t  = 0.7978845608028654f * (x + 0.044715f*x3);
  float e  = __expf(2.0f*t);
  float th = 1.0f - 2.0f/(e + 1.0f);   // tanh(t), inf-safe
  return 0.5f * x * (1.0f + th);
}

// ---------------- weight fp32 [K][N] -> bf16 W^T [N][K] ----------------
__global__ void wcvt_kernel(const float* __restrict__ W, unsigned short* __restrict__ WT,
                            int K, int N) {
  __shared__ float tile[32][33];
  int tx = threadIdx.x & 31, ty = threadIdx.x >> 5;       // 32 x 8
  int kb = blockIdx.x * 32, nb = blockIdx.y * 32;
  #pragma unroll
  for (int r = 0; r < 32; r += 8)
    tile[ty + r][tx] = W[(size_t)(kb + ty + r) * N + nb + tx];
  __syncthreads();
  #pragma unroll
  for (int r = 0; r < 32; r += 8)
    WT[(size_t)(nb + ty + r) * K + kb + tx] = f2bf(tile[tx][ty + r]);
}

// ---------------- layernorm fp32 -> bf16 ----------------
__global__ void ln_kernel(const float* __restrict__ X, const float* __restrict__ g,
                          const float* __restrict__ bb, unsigned short* __restrict__ O) {
  int row = blockIdx.x, t = threadIdx.x;
  const float4* xr = (const float4*)(X + (size_t)row * Cc);
  float4 v = xr[t];
  float s = v.x + v.y + v.z + v.w;
  float q = v.x*v.x + v.y*v.y + v.z*v.z + v.w*v.w;
  #pragma unroll
  for (int o = 32; o > 0; o >>= 1) { s += __shfl_xor(s, o); q += __shfl_xor(q, o); }
  __shared__ float ss[4], sq[4];
  int w = t >> 6;
  if ((t & 63) == 0) { ss[w] = s; sq[w] = q; }
  __syncthreads();
  s = ss[0] + ss[1] + ss[2] + ss[3];
  q = sq[0] + sq[1] + sq[2] + sq[3];
  float mu  = s * (1.0f/Cc);
  float var = q * (1.0f/Cc) - mu*mu;
  float rstd = rsqrtf(var + 1e-5f);
  float4 gv = ((const float4*)g)[t], bv = ((const float4*)bb)[t];
  ushort4 o4;
  o4.x = f2bf((v.x-mu)*rstd*gv.x + bv.x);
  o4.y = f2bf((v.y-mu)*rstd*gv.y + bv.y);
  o4.z = f2bf((v.z-mu)*rstd*gv.z + bv.z);
  o4.w = f2bf((v.w-mu)*rstd*gv.w + bv.w);
  ((ushort4*)(O + (size_t)row * Cc))[t] = o4;
}

// ---------------- GEMM (unchanged from round 0; passed refcheck) ----------------
template<int MODE>
__launch_bounds__(256, 2)
__global__ void gemm_kernel(const unsigned short* __restrict__ A,
                            const unsigned short* __restrict__ BT,
                            const float* __restrict__ bias,
                            const float* __restrict__ res,
                            void* __restrict__ Cout,
                            int N, int K) {
  __shared__ unsigned short As[128*32];
  __shared__ unsigned short Bs[128*32];
  int tid  = threadIdx.x;
  int lane = tid & 63, w = tid >> 6;
  int wr = w >> 1, wc = w & 1;
  int bm = blockIdx.x, bn = blockIdx.y;

  f32x4 acc[4][4];
  #pragma unroll
  for (int m = 0; m < 4; ++m)
    #pragma unroll
    for (int n = 0; n < 4; ++n) acc[m][n] = (f32x4){0.f,0.f,0.f,0.f};

  int arow   = tid >> 2;
  int kchunk = (tid & 3) * 8;
  const unsigned short* Ag = A  + (size_t)(bm*128 + arow) * K + kchunk;
  const unsigned short* Bg = BT + (size_t)(bn*128 + arow) * K + kchunk;
  int nk = K >> 5;

  for (int kt = 0; kt < nk; ++kt) {
    if (kt) __syncthreads();
    const unsigned short* ag = Ag + kt*32;
    const unsigned short* bg = Bg + kt*32;
    __builtin_amdgcn_global_load_lds((const __attribute__((address_space(1))) void*)ag,
        (__attribute__((address_space(3))) void*)(As + w*512), 16, 0, 0);
    __builtin_amdgcn_global_load_lds((const __attribute__((address_space(1))) void*)(ag + (size_t)64*K),
        (__attribute__((address_space(3))) void*)(As + 2048 + w*512), 16, 0, 0);
    __builtin_amdgcn_global_load_lds((const __attribute__((address_space(1))) void*)bg,
        (__attribute__((address_space(3))) void*)(Bs + w*512), 16, 0, 0);
    __builtin_amdgcn_global_load_lds((const __attribute__((address_space(1))) void*)(bg + (size_t)64*K),
        (__attribute__((address_space(3))) void*)(Bs + 2048 + w*512), 16, 0, 0);
    __syncthreads();

    bf16x8 af[4], bfr[4];
    #pragma unroll
    for (int m = 0; m < 4; ++m)
      af[m] = *(const bf16x8*)(As + (wr*64 + m*16 + (lane&15))*32 + (lane>>4)*8);
    #pragma unroll
    for (int n = 0; n < 4; ++n)
      bfr[n] = *(const bf16x8*)(Bs + (wc*64 + n*16 + (lane&15))*32 + (lane>>4)*8);
    #pragma unroll
    for (int m = 0; m < 4; ++m)
      #pragma unroll
      for (int n = 0; n < 4; ++n)
        acc[m][n] = __builtin_amdgcn_mfma_f32_16x16x32_bf16(af[m], bfr[n], acc[m][n], 0, 0, 0);
  }

  int r0 = bm*128 + wr*64;
  int c0 = bn*128 + wc*64;
  int lr = (lane >> 4) * 4;
  int lc = lane & 15;
  #pragma unroll
  for (int m = 0; m < 4; ++m) {
    #pragma unroll
    for (int n = 0; n < 4; ++n) {
      int col = c0 + n*16 + lc;
      float bv = bias[col];
      #pragma unroll
      for (int i = 0; i < 4; ++i) {
        int row = r0 + m*16 + lr + i;
        float v = acc[m][n][i] + bv;
        if (MODE == 1 || MODE == 3) v += res[(size_t)row * N + col];
        if (MODE == 2) v = gelu_(v);
        if (MODE == 0 || MODE == 2)
          ((unsigned short*)Cout)[(size_t)row * N + col] = f2bf(v);
        else
          ((float*)Cout)[(size_t)row * N + col] = v;
      }
    }
  }
}

// ---------------- V transpose: qkv V-third -> vtb[bh][64 d][2048 k] bf16 -------
__global__ void vtr_kernel(const unsigned short* __restrict__ qkv,
                           unsigned short* __restrict__ vtb) {
  __shared__ unsigned short Tl[64][72];
  int tid = threadIdx.x;
  int bh = blockIdx.x, tc = blockIdx.y;
  int b = bh >> 4, h = bh & 15;
  int r = tid >> 2, c0 = (tid & 3) * 16;
  const unsigned short* src = qkv + (size_t)(b*Tt + tc*64 + r)*3072 + 2048 + h*64 + c0;
  *(int4*)&Tl[r][c0]     = *(const int4*)(src);
  *(int4*)&Tl[r][c0 + 8] = *(const int4*)(src + 8);
  __syncthreads();
  int d = tid >> 2, k0 = (tid & 3) * 16;
  ushort4 o[4];
  #pragma unroll
  for (int jj = 0; jj < 4; ++jj) {
    o[jj].x = Tl[k0 + jj*4 + 0][d];
    o[jj].y = Tl[k0 + jj*4 + 1][d];
    o[jj].z = Tl[k0 + jj*4 + 2][d];
    o[jj].w = Tl[k0 + jj*4 + 3][d];
  }
  unsigned short* dst = vtb + ((size_t)(bh*64 + d))*2048 + tc*64 + k0;
  *(int4*)(dst)     = *(int4*)&o[0];
  *(int4*)(dst + 8) = *(int4*)&o[2];
}

// ---------------- MFMA flash attention ----------------
// block: 128 q-rows of one (b,h); 8 waves x 16 q-rows; KV tiles of 64 keys.
// S^T = mfma(K, Q): lane holds 16 S-values for q = lane&15 (k-axis in-lane).
// P relayout via per-wave LDS; PV = mfma(P, V) with V^T staged (k-contiguous).
__global__ __launch_bounds__(512, 4)
void attn_kernel(const unsigned short* __restrict__ qkv,
                 const unsigned short* __restrict__ vtb,
                 unsigned short* __restrict__ att) {
  __shared__ __align__(16) char smem[36864];   // K 8KB | VT 8KB | P 8x2560B
  int tid  = threadIdx.x;
  int lane = tid & 63, w = tid >> 6;
  int g = lane >> 4, ql = lane & 15;

  int bid = blockIdx.x;
  int bh = bid & 31;
  int jj = bid >> 5;
  int j  = (jj < 8) ? (2*jj) : (31 - 2*jj);    // pair long+short causal blocks
  int b = bh >> 4, h = bh & 15;
  int Q0 = j * 128;
  int qbase = Q0 + w * 16;
  char* Pb = smem + 16384 + w * 2560;          // per-wave P: [16 q][80 shorts]

  // Q fragments (row = q = lane&15, k = d = g*8+j, two halves)
  const unsigned short* qrow = qkv + (size_t)(b*Tt + qbase + ql) * 3072 + h*64;
  bf16x8 qf0 = *(const bf16x8*)(qrow + g*8);
  bf16x8 qf1 = *(const bf16x8*)(qrow + 32 + g*8);

  f32x4 O[4];
  #pragma unroll
  for (int d = 0; d < 4; ++d) O[d] = (f32x4){0.f,0.f,0.f,0.f};
  float mrun = -1e30f, lrun = 0.f;

  int nt = Q0/64 + 2;

  // staging roles: thread -> (row = tid>>3, 8 bf16 at col (tid&7)*8), XOR-swizzled
  int srow = tid >> 3;
  int scol = (tid & 7) * 8;
  int wr_off = srow*128 + ((scol*2) ^ ((srow & 7) << 4));
  const unsigned short* Kg = qkv + (size_t)(b*Tt + srow)*3072 + 1024 + h*64 + scol;
  const unsigned short* Vg = vtb + ((size_t)(bh*64 + srow))*2048 + scol;

  int4 kreg = *(const int4*)(Kg);
  int4 vreg = *(const int4*)(Vg);

  for (int t0 = 0; t0 < nt; ++t0) {
    __syncthreads();                       // LDS free
    *(int4*)(smem + wr_off)        = kreg;
    *(int4*)(smem + 8192 + wr_off) = vreg;
    __syncthreads();                       // LDS ready
    if (t0 + 1 < nt) {                     // prefetch next tile (overlaps compute)
      kreg = *(const int4*)(Kg + (size_t)(t0+1)*64*3072);
      vreg = *(const int4*)(Vg + (t0+1)*64);
    }
    if (t0*64 > qbase + 15) continue;      // wave fully masked: barriers only

    bool full = (t0*64 + 63) <= qbase;
    float ps[16];
    #pragma unroll
    for (int s = 0; s < 4; ++s) {
      int krow = s*16 + ql;
      int kb0 = krow*128 + (( g*16      ) ^ ((krow&7)<<4));
      int kb1 = krow*128 + (( g*16 + 64 ) ^ ((krow&7)<<4));
      bf16x8 kf0 = *(const bf16x8*)(smem + kb0);
      bf16x8 kf1 = *(const bf16x8*)(smem + kb1);
      f32x4 a = (f32x4){0.f,0.f,0.f,0.f};
      a = __builtin_amdgcn_mfma_f32_16x16x32_bf16(kf0, qf0, a, 0, 0, 0);
      a = __builtin_amdgcn_mfma_f32_16x16x32_bf16(kf1, qf1, a, 0, 0, 0);
      #pragma unroll
      for (int i = 0; i < 4; ++i) ps[s*4+i] = a[i] * 0.125f;
    }
    if (!full) {
      #pragma unroll
      for (int s = 0; s < 4; ++s)
        #pragma unroll
        for (int i = 0; i < 4; ++i)
          if (t0*64 + s*16 + g*4 + i > qbase + ql) ps[s*4+i] = -1e30f;
    }
    float tm = ps[0];
    #pragma unroll
    for (int i = 1; i < 16; ++i) tm = fmaxf(tm, ps[i]);
    tm = fmaxf(tm, __shfl_xor(tm, 16));
    tm = fmaxf(tm, __shfl_xor(tm, 32));
    float mnew = fmaxf(mrun, tm);
    float corr = __expf(mrun - mnew);
    float tsum = 0.f;
    #pragma unroll
    for (int s = 0; s < 4; ++s) {
      float e0 = __expf(ps[s*4+0] - mnew);
      float e1 = __expf(ps[s*4+1] - mnew);
      float e2 = __expf(ps[s*4+2] - mnew);
      float e3 = __expf(ps[s*4+3] - mnew);
      tsum += (e0 + e1) + (e2 + e3);
      ushort4 pk;
      pk.x = f2bf(e0); pk.y = f2bf(e1); pk.z = f2bf(e2); pk.w = f2bf(e3);
      *(ushort4*)(Pb + ql*160 + s*32 + g*8) = pk;   // P[q][k=s*16+g*4+i]
    }
    tsum += __shfl_xor(tsum, 16);
    tsum += __shfl_xor(tsum, 32);
    lrun = lrun * corr + tsum;
    mrun = mnew;

    float c0 = __shfl(corr, g*4 + 0);
    float c1 = __shfl(corr, g*4 + 1);
    float c2 = __shfl(corr, g*4 + 2);
    float c3 = __shfl(corr, g*4 + 3);
    #pragma unroll
    for (int d = 0; d < 4; ++d) {
      O[d][0] *= c0; O[d][1] *= c1; O[d][2] *= c2; O[d][3] *= c3;
    }
    #pragma unroll
    for (int kk = 0; kk < 2; ++kk) {
      bf16x8 pf = *(const bf16x8*)(Pb + ql*160 + kk*64 + g*16);  // P[q][kk*32+g*8+j]
      #pragma unroll
      for (int d = 0; d < 4; ++d) {
        int drow = d*16 + ql;
        int vb = drow*128 + ((kk*64 + g*16) ^ ((drow&7)<<4));
        bf16x8 vf = *(const bf16x8*)(smem + 8192 + vb);          // V[k][d] via VT
        O[d] = __builtin_amdgcn_mfma_f32_16x16x32_bf16(pf, vf, O[d], 0, 0, 0);
      }
    }
  }

  float l0 = __shfl(lrun, g*4 + 0);
  float l1 = __shfl(lrun, g*4 + 1);
  float l2 = __shfl(lrun, g*4 + 2);
  float l3 = __shfl(lrun, g*4 + 3);
  #pragma unroll
  for (int d = 0; d < 4; ++d) {
    size_t base = (size_t)(b*Tt + qbase)*Cc + h*64 + d*16 + ql;
    att[base + (size_t)(g*4+0)*Cc] = f2bf(O[d][0] / l0);
    att[base + (size_t)(g*4+1)*Cc] = f2bf(O[d][1] / l1);
    att[base + (size_t)(g*4+2)*Cc] = f2bf(O[d][2] / l2);
    att[base + (size_t)(g*4+3)*Cc] = f2bf(O[d][3] / l3);
  }
}

// ---------------- launch ----------------
extern "C" void kernel_launch(void* const* d_in, const int* in_sizes, int n_in,
                              void* d_out, int out_size, void* d_ws, size_t ws_size,
                              hipStream_t stream) {
  const float* x    = (const float*)d_in[0];
  const float* ln1g = (const float*)d_in[1];
  const float* ln1b = (const float*)d_in[2];
  const float* Wqkv = (const float*)d_in[3];
  const float* bqkv = (const float*)d_in[4];
  const float* Wout = (const float*)d_in[5];
  const float* bout = (const float*)d_in[6];
  const float* ln2g = (const float*)d_in[7];
  const float* ln2b = (const float*)d_in[8];
  const float* Wfc1 = (const float*)d_in[9];
  const float* bfc1 = (const float*)d_in[10];
  const float* Wfc2 = (const float*)d_in[11];
  const float* bfc2 = (const float*)d_in[12];

  char* ws = (char*)d_ws;
  unsigned short* wqkvT = (unsigned short*)(ws);                 // 6 MB  [3072][1024]
  unsigned short* woutT = (unsigned short*)(ws + (6u<<20));      // 2 MB  [1024][1024]
  unsigned short* wfc1T = (unsigned short*)(ws + (8u<<20));      // 8 MB  [4096][1024]
  unsigned short* wfc2T = (unsigned short*)(ws + (16u<<20));     // 8 MB  [1024][4096]
  unsigned short* vtb   = (unsigned short*)(ws + (24u<<20));     // 8 MB  (dead before temp written)
  float*          temp  = (float*)(ws + (24u<<20));              // 16 MB [4096][1024] (after attn)
  unsigned short* hbuf  = (unsigned short*)(ws + (40u<<20));     // 8 MB  [4096][1024]
  unsigned short* qkvb  = (unsigned short*)(ws + (48u<<20));     // 24 MB [4096][3072]
  unsigned short* attb  = (unsigned short*)(ws + (72u<<20));     // 8 MB  [4096][1024]
  unsigned short* a1b   = (unsigned short*)(ws + (48u<<20));     // 32 MB (reuses qkv+att)

  dim3 b256(256);
  wcvt_kernel<<<dim3(1024/32, 3072/32), b256, 0, stream>>>(Wqkv, wqkvT, 1024, 3072);
  wcvt_kernel<<<dim3(1024/32, 1024/32), b256, 0, stream>>>(Wout, woutT, 1024, 1024);
  wcvt_kernel<<<dim3(1024/32, 4096/32), b256, 0, stream>>>(Wfc1, wfc1T, 1024, 4096);
  wcvt_kernel<<<dim3(4096/32, 1024/32), b256, 0, stream>>>(Wfc2, wfc2T, 4096, 1024);

  ln_kernel<<<Mm, b256, 0, stream>>>(x, ln1g, ln1b, hbuf);
  gemm_kernel<0><<<dim3(Mm/128, 3072/128), b256, 0, stream>>>(hbuf, wqkvT, bqkv, nullptr, qkvb, 3072, 1024);
  vtr_kernel<<<dim3(32, 32), b256, 0, stream>>>(qkvb, vtb);
  attn_kernel<<<dim3(512), 512, 0, stream>>>(qkvb, vtb, attb);
  gemm_kernel<1><<<dim3(Mm/128, 1024/128), b256, 0, stream>>>(attb, woutT, bout, x, temp, 1024, 1024);
  ln_kernel<<<Mm, b256, 0, stream>>>(temp, ln2g, ln2b, hbuf);
  gemm_kernel<2><<<dim3(Mm/128, 4096/128), b256, 0, stream>>>(hbuf, wfc1T, bfc1, nullptr, a1b, 4096, 1024);
  gemm_kernel<3><<<dim3(Mm/128, 1024/128), b256, 0, stream>>>(a1b, wfc2T, bfc2, temp, d_out, 1024, 4096);
}

// Round 4
// 368.435 us; speedup vs baseline: 3.5583x; 1.0186x over previous
//
#include <hip/hip_runtime.h>
#include <stdint.h>

// ---------------- constants ----------------
#define Bb 2
#define Tt 2048
#define Cc 1024
#define Hh 16
#define HD 64
#define Mm (Bb*Tt)   // 4096

typedef __bf16 bf16x8 __attribute__((ext_vector_type(8)));
typedef float  f32x4  __attribute__((ext_vector_type(4)));

#define DEV static __device__ __forceinline__

DEV float asfloat_(uint32_t u){ union{uint32_t u; float f;} x; x.u=u; return x.f; }
DEV uint32_t asuint_(float f){ union{float f; uint32_t u;} x; x.f=f; return x.u; }
DEV unsigned short f2bf(float f){
  uint32_t u = asuint_(f);
  uint32_t r = (u + 0x7fffu + ((u>>16)&1u)) >> 16;
  return (unsigned short)r;
}
DEV float gelu_(float x){
  float x3 = x*x*x;
  float t  = 0.7978845608028654f * (x + 0.044715f*x3);
  float e  = __expf(2.0f*t);
  float th = 1.0f - 2.0f/(e + 1.0f);   // tanh(t), inf-safe
  return 0.5f * x * (1.0f + th);
}

#define GLL(gsrc, ldst) __builtin_amdgcn_global_load_lds( \
    (const __attribute__((address_space(1))) void*)(gsrc), \
    (__attribute__((address_space(3))) void*)(ldst), 16, 0, 0)

// ---------------- weight fp32 [K][N] -> bf16 W^T [N][K] ----------------
__global__ void wcvt_kernel(const float* __restrict__ W, unsigned short* __restrict__ WT,
                            int K, int N) {
  __shared__ float tile[32][33];
  int tx = threadIdx.x & 31, ty = threadIdx.x >> 5;       // 32 x 8
  int kb = blockIdx.x * 32, nb = blockIdx.y * 32;
  #pragma unroll
  for (int r = 0; r < 32; r += 8)
    tile[ty + r][tx] = W[(size_t)(kb + ty + r) * N + nb + tx];
  __syncthreads();
  #pragma unroll
  for (int r = 0; r < 32; r += 8)
    WT[(size_t)(nb + ty + r) * K + kb + tx] = f2bf(tile[tx][ty + r]);
}

// ---------------- layernorm fp32 -> bf16 ----------------
__global__ void ln_kernel(const float* __restrict__ X, const float* __restrict__ g,
                          const float* __restrict__ bb, unsigned short* __restrict__ O) {
  int row = blockIdx.x, t = threadIdx.x;
  const float4* xr = (const float4*)(X + (size_t)row * Cc);
  float4 v = xr[t];
  float s = v.x + v.y + v.z + v.w;
  float q = v.x*v.x + v.y*v.y + v.z*v.z + v.w*v.w;
  #pragma unroll
  for (int o = 32; o > 0; o >>= 1) { s += __shfl_xor(s, o); q += __shfl_xor(q, o); }
  __shared__ float ss[4], sq[4];
  int w = t >> 6;
  if ((t & 63) == 0) { ss[w] = s; sq[w] = q; }
  __syncthreads();
  s = ss[0] + ss[1] + ss[2] + ss[3];
  q = sq[0] + sq[1] + sq[2] + sq[3];
  float mu  = s * (1.0f/Cc);
  float var = q * (1.0f/Cc) - mu*mu;
  float rstd = rsqrtf(var + 1e-5f);
  float4 gv = ((const float4*)g)[t], bv = ((const float4*)bb)[t];
  ushort4 o4;
  o4.x = f2bf((v.x-mu)*rstd*gv.x + bv.x);
  o4.y = f2bf((v.y-mu)*rstd*gv.y + bv.y);
  o4.z = f2bf((v.z-mu)*rstd*gv.z + bv.z);
  o4.w = f2bf((v.w-mu)*rstd*gv.w + bv.w);
  ((ushort4*)(O + (size_t)row * Cc))[t] = o4;
}

// ---------------- GEMM: 128x128 tile, 8 waves (2x4), BK=64, swizzled LDS ----------
// MODE 0: +bias -> bf16 out        (qkv)
// MODE 1: +bias +res(f32) -> f32   (out-proj + x)
// MODE 2: +bias, gelu -> bf16      (fc1)
// MODE 3: +bias +res(f32) -> f32   (fc2 + temp)
template<int MODE>
__launch_bounds__(512, 4)
__global__ void gemm_kernel(const unsigned short* __restrict__ A,
                            const unsigned short* __restrict__ BT,
                            const float* __restrict__ bias,
                            const float* __restrict__ res,
                            void* __restrict__ Cout,
                            int N, int K) {
  __shared__ unsigned short As[128*64];   // 16 KB, row-major [128][64], source pre-swizzled
  __shared__ unsigned short Bs[128*64];   // 16 KB
  int tid  = threadIdx.x;
  int lane = tid & 63, w = tid >> 6;
  int wr = w >> 2, wc = w & 3;            // wave tile: 64 (M) x 32 (N)
  int g = lane >> 4, ql = lane & 15;
  int bm = blockIdx.x, bn = blockIdx.y;

  f32x4 acc[4][2];
  #pragma unroll
  for (int m = 0; m < 4; ++m)
    #pragma unroll
    for (int n = 0; n < 2; ++n) acc[m][n] = (f32x4){0.f,0.f,0.f,0.f};

  // staging: thread -> row r = tid>>3 (0..63, +64 second half), 8 bf16 at
  // swizzled source column (cc ^ (r&7))*8; LDS dest stays linear (rule #21).
  int r  = tid >> 3;
  int cc = tid & 7;
  int sc = (cc ^ (r & 7)) * 8;
  const unsigned short* Ag = A  + (size_t)(bm*128 + r) * K + sc;
  const unsigned short* Bg = BT + (size_t)(bn*128 + r) * K + sc;
  int sw = (ql & 7) << 3;                 // fragment-read swizzle (shorts)
  int nk = K >> 6;

  for (int kt = 0; kt < nk; ++kt) {
    if (kt) __syncthreads();
    const unsigned short* ag = Ag + kt*64;
    const unsigned short* bg = Bg + kt*64;
    GLL(ag,                  As + w*512);
    GLL(ag + (size_t)64*K,   As + 4096 + w*512);
    GLL(bg,                  Bs + w*512);
    GLL(bg + (size_t)64*K,   Bs + 4096 + w*512);
    __syncthreads();

    #pragma unroll
    for (int kk = 0; kk < 2; ++kk) {
      int col = (kk*32 + g*8) ^ sw;
      bf16x8 af[4], bf2[2];
      #pragma unroll
      for (int m = 0; m < 4; ++m)
        af[m] = *(const bf16x8*)(As + (wr*64 + m*16 + ql)*64 + col);
      #pragma unroll
      for (int n = 0; n < 2; ++n)
        bf2[n] = *(const bf16x8*)(Bs + (wc*32 + n*16 + ql)*64 + col);
      #pragma unroll
      for (int m = 0; m < 4; ++m)
        #pragma unroll
        for (int n = 0; n < 2; ++n)
          acc[m][n] = __builtin_amdgcn_mfma_f32_16x16x32_bf16(af[m], bf2[n], acc[m][n], 0, 0, 0);
    }
  }

  int r0 = bm*128 + wr*64;
  int c0 = bn*128 + wc*32;
  int lr = g * 4;
  #pragma unroll
  for (int m = 0; m < 4; ++m) {
    #pragma unroll
    for (int n = 0; n < 2; ++n) {
      int col = c0 + n*16 + ql;
      float bv = bias[col];
      #pragma unroll
      for (int i = 0; i < 4; ++i) {
        int row = r0 + m*16 + lr + i;
        float v = acc[m][n][i] + bv;
        if (MODE == 1 || MODE == 3) v += res[(size_t)row * N + col];
        if (MODE == 2) v = gelu_(v);
        if (MODE == 0 || MODE == 2)
          ((unsigned short*)Cout)[(size_t)row * N + col] = f2bf(v);
        else
          ((float*)Cout)[(size_t)row * N + col] = v;
      }
    }
  }
}

// ---------------- V transpose: qkv V-third -> vtb[bh][64 d][2048 k] bf16 -------
__global__ void vtr_kernel(const unsigned short* __restrict__ qkv,
                           unsigned short* __restrict__ vtb) {
  __shared__ unsigned short Tl[64][72];
  int tid = threadIdx.x;
  int bh = blockIdx.x, tc = blockIdx.y;
  int b = bh >> 4, h = bh & 15;
  int r = tid >> 2, c0 = (tid & 3) * 16;
  const unsigned short* src = qkv + (size_t)(b*Tt + tc*64 + r)*3072 + 2048 + h*64 + c0;
  *(int4*)&Tl[r][c0]     = *(const int4*)(src);
  *(int4*)&Tl[r][c0 + 8] = *(const int4*)(src + 8);
  __syncthreads();
  int d = tid >> 2, k0 = (tid & 3) * 16;
  ushort4 o[4];
  #pragma unroll
  for (int jj = 0; jj < 4; ++jj) {
    o[jj].x = Tl[k0 + jj*4 + 0][d];
    o[jj].y = Tl[k0 + jj*4 + 1][d];
    o[jj].z = Tl[k0 + jj*4 + 2][d];
    o[jj].w = Tl[k0 + jj*4 + 3][d];
  }
  unsigned short* dst = vtb + ((size_t)(bh*64 + d))*2048 + tc*64 + k0;
  *(int4*)(dst)     = *(int4*)&o[0];
  *(int4*)(dst + 8) = *(int4*)&o[2];
}

// ---------------- MFMA flash attention (unchanged, passed refcheck) ----------------
__global__ __launch_bounds__(512, 4)
void attn_kernel(const unsigned short* __restrict__ qkv,
                 const unsigned short* __restrict__ vtb,
                 unsigned short* __restrict__ att) {
  __shared__ __align__(16) char smem[36864];   // K 8KB | VT 8KB | P 8x2560B
  int tid  = threadIdx.x;
  int lane = tid & 63, w = tid >> 6;
  int g = lane >> 4, ql = lane & 15;

  int bid = blockIdx.x;
  int bh = bid & 31;
  int jj = bid >> 5;
  int j  = (jj < 8) ? (2*jj) : (31 - 2*jj);    // pair long+short causal blocks
  int b = bh >> 4, h = bh & 15;
  int Q0 = j * 128;
  int qbase = Q0 + w * 16;
  char* Pb = smem + 16384 + w * 2560;          // per-wave P: [16 q][80 shorts]

  const unsigned short* qrow = qkv + (size_t)(b*Tt + qbase + ql) * 3072 + h*64;
  bf16x8 qf0 = *(const bf16x8*)(qrow + g*8);
  bf16x8 qf1 = *(const bf16x8*)(qrow + 32 + g*8);

  f32x4 O[4];
  #pragma unroll
  for (int d = 0; d < 4; ++d) O[d] = (f32x4){0.f,0.f,0.f,0.f};
  float mrun = -1e30f, lrun = 0.f;

  int nt = Q0/64 + 2;

  int srow = tid >> 3;
  int scol = (tid & 7) * 8;
  int wr_off = srow*128 + ((scol*2) ^ ((srow & 7) << 4));
  const unsigned short* Kg = qkv + (size_t)(b*Tt + srow)*3072 + 1024 + h*64 + scol;
  const unsigned short* Vg = vtb + ((size_t)(bh*64 + srow))*2048 + scol;

  int4 kreg = *(const int4*)(Kg);
  int4 vreg = *(const int4*)(Vg);

  for (int t0 = 0; t0 < nt; ++t0) {
    __syncthreads();                       // LDS free
    *(int4*)(smem + wr_off)        = kreg;
    *(int4*)(smem + 8192 + wr_off) = vreg;
    __syncthreads();                       // LDS ready
    if (t0 + 1 < nt) {
      kreg = *(const int4*)(Kg + (size_t)(t0+1)*64*3072);
      vreg = *(const int4*)(Vg + (t0+1)*64);
    }
    if (t0*64 > qbase + 15) continue;

    bool full = (t0*64 + 63) <= qbase;
    float ps[16];
    #pragma unroll
    for (int s = 0; s < 4; ++s) {
      int krow = s*16 + ql;
      int kb0 = krow*128 + (( g*16      ) ^ ((krow&7)<<4));
      int kb1 = krow*128 + (( g*16 + 64 ) ^ ((krow&7)<<4));
      bf16x8 kf0 = *(const bf16x8*)(smem + kb0);
      bf16x8 kf1 = *(const bf16x8*)(smem + kb1);
      f32x4 a = (f32x4){0.f,0.f,0.f,0.f};
      a = __builtin_amdgcn_mfma_f32_16x16x32_bf16(kf0, qf0, a, 0, 0, 0);
      a = __builtin_amdgcn_mfma_f32_16x16x32_bf16(kf1, qf1, a, 0, 0, 0);
      #pragma unroll
      for (int i = 0; i < 4; ++i) ps[s*4+i] = a[i] * 0.125f;
    }
    if (!full) {
      #pragma unroll
      for (int s = 0; s < 4; ++s)
        #pragma unroll
        for (int i = 0; i < 4; ++i)
          if (t0*64 + s*16 + g*4 + i > qbase + ql) ps[s*4+i] = -1e30f;
    }
    float tm = ps[0];
    #pragma unroll
    for (int i = 1; i < 16; ++i) tm = fmaxf(tm, ps[i]);
    tm = fmaxf(tm, __shfl_xor(tm, 16));
    tm = fmaxf(tm, __shfl_xor(tm, 32));
    float mnew = fmaxf(mrun, tm);
    float corr = __expf(mrun - mnew);
    float tsum = 0.f;
    #pragma unroll
    for (int s = 0; s < 4; ++s) {
      float e0 = __expf(ps[s*4+0] - mnew);
      float e1 = __expf(ps[s*4+1] - mnew);
      float e2 = __expf(ps[s*4+2] - mnew);
      float e3 = __expf(ps[s*4+3] - mnew);
      tsum += (e0 + e1) + (e2 + e3);
      ushort4 pk;
      pk.x = f2bf(e0); pk.y = f2bf(e1); pk.z = f2bf(e2); pk.w = f2bf(e3);
      *(ushort4*)(Pb + ql*160 + s*32 + g*8) = pk;
    }
    tsum += __shfl_xor(tsum, 16);
    tsum += __shfl_xor(tsum, 32);
    lrun = lrun * corr + tsum;
    mrun = mnew;

    float c0 = __shfl(corr, g*4 + 0);
    float c1 = __shfl(corr, g*4 + 1);
    float c2 = __shfl(corr, g*4 + 2);
    float c3 = __shfl(corr, g*4 + 3);
    #pragma unroll
    for (int d = 0; d < 4; ++d) {
      O[d][0] *= c0; O[d][1] *= c1; O[d][2] *= c2; O[d][3] *= c3;
    }
    #pragma unroll
    for (int kk = 0; kk < 2; ++kk) {
      bf16x8 pf = *(const bf16x8*)(Pb + ql*160 + kk*64 + g*16);
      #pragma unroll
      for (int d = 0; d < 4; ++d) {
        int drow = d*16 + ql;
        int vb = drow*128 + ((kk*64 + g*16) ^ ((drow&7)<<4));
        bf16x8 vf = *(const bf16x8*)(smem + 8192 + vb);
        O[d] = __builtin_amdgcn_mfma_f32_16x16x32_bf16(pf, vf, O[d], 0, 0, 0);
      }
    }
  }

  float l0 = __shfl(lrun, g*4 + 0);
  float l1 = __shfl(lrun, g*4 + 1);
  float l2 = __shfl(lrun, g*4 + 2);
  float l3 = __shfl(lrun, g*4 + 3);
  #pragma unroll
  for (int d = 0; d < 4; ++d) {
    size_t base = (size_t)(b*Tt + qbase)*Cc + h*64 + d*16 + ql;
    att[base + (size_t)(g*4+0)*Cc] = f2bf(O[d][0] / l0);
    att[base + (size_t)(g*4+1)*Cc] = f2bf(O[d][1] / l1);
    att[base + (size_t)(g*4+2)*Cc] = f2bf(O[d][2] / l2);
    att[base + (size_t)(g*4+3)*Cc] = f2bf(O[d][3] / l3);
  }
}

// ---------------- launch ----------------
extern "C" void kernel_launch(void* const* d_in, const int* in_sizes, int n_in,
                              void* d_out, int out_size, void* d_ws, size_t ws_size,
                              hipStream_t stream) {
  const float* x    = (const float*)d_in[0];
  const float* ln1g = (const float*)d_in[1];
  const float* ln1b = (const float*)d_in[2];
  const float* Wqkv = (const float*)d_in[3];
  const float* bqkv = (const float*)d_in[4];
  const float* Wout = (const float*)d_in[5];
  const float* bout = (const float*)d_in[6];
  const float* ln2g = (const float*)d_in[7];
  const float* ln2b = (const float*)d_in[8];
  const float* Wfc1 = (const float*)d_in[9];
  const float* bfc1 = (const float*)d_in[10];
  const float* Wfc2 = (const float*)d_in[11];
  const float* bfc2 = (const float*)d_in[12];

  char* ws = (char*)d_ws;
  unsigned short* wqkvT = (unsigned short*)(ws);                 // 6 MB  [3072][1024]
  unsigned short* woutT = (unsigned short*)(ws + (6u<<20));      // 2 MB  [1024][1024]
  unsigned short* wfc1T = (unsigned short*)(ws + (8u<<20));      // 8 MB  [4096][1024]
  unsigned short* wfc2T = (unsigned short*)(ws + (16u<<20));     // 8 MB  [1024][4096]
  unsigned short* vtb   = (unsigned short*)(ws + (24u<<20));     // 8 MB  (dead before temp written)
  float*          temp  = (float*)(ws + (24u<<20));              // 16 MB [4096][1024] (after attn)
  unsigned short* hbuf  = (unsigned short*)(ws + (40u<<20));     // 8 MB  [4096][1024]
  unsigned short* qkvb  = (unsigned short*)(ws + (48u<<20));     // 24 MB [4096][3072]
  unsigned short* attb  = (unsigned short*)(ws + (72u<<20));     // 8 MB  [4096][1024]
  unsigned short* a1b   = (unsigned short*)(ws + (48u<<20));     // 32 MB (reuses qkv+att)

  dim3 b256(256), b512(512);
  wcvt_kernel<<<dim3(1024/32, 3072/32), b256, 0, stream>>>(Wqkv, wqkvT, 1024, 3072);
  wcvt_kernel<<<dim3(1024/32, 1024/32), b256, 0, stream>>>(Wout, woutT, 1024, 1024);
  wcvt_kernel<<<dim3(1024/32, 4096/32), b256, 0, stream>>>(Wfc1, wfc1T, 1024, 4096);
  wcvt_kernel<<<dim3(4096/32, 1024/32), b256, 0, stream>>>(Wfc2, wfc2T, 4096, 1024);

  ln_kernel<<<Mm, b256, 0, stream>>>(x, ln1g, ln1b, hbuf);
  gemm_kernel<0><<<dim3(Mm/128, 3072/128), b512, 0, stream>>>(hbuf, wqkvT, bqkv, nullptr, qkvb, 3072, 1024);
  vtr_kernel<<<dim3(32, 32), b256, 0, stream>>>(qkvb, vtb);
  attn_kernel<<<dim3(512), 512, 0, stream>>>(qkvb, vtb, attb);
  gemm_kernel<1><<<dim3(Mm/128, 1024/128), b512, 0, stream>>>(attb, woutT, bout, x, temp, 1024, 1024);
  ln_kernel<<<Mm, b256, 0, stream>>>(temp, ln2g, ln2b, hbuf);
  gemm_kernel<2><<<dim3(Mm/128, 4096/128), b512, 0, stream>>>(hbuf, wfc1T, bfc1, nullptr, a1b, 4096, 1024);
  gemm_kernel<3><<<dim3(Mm/128, 1024/128), b512, 0, stream>>>(a1b, wfc2T, bfc2, temp, d_out, 1024, 4096);
}

// Round 6
// 356.052 us; speedup vs baseline: 3.6821x; 1.0348x over previous
//
#include <hip/hip_runtime.h>
#include <stdint.h>

// ---------------- constants ----------------
#define Bb 2
#define Tt 2048
#define Cc 1024
#define Hh 16
#define HD 64
#define Mm (Bb*Tt)   // 4096

typedef __bf16 bf16x8 __attribute__((ext_vector_type(8)));
typedef float  f32x4  __attribute__((ext_vector_type(4)));

#define DEV static __device__ __forceinline__

DEV float asfloat_(uint32_t u){ union{uint32_t u; float f;} x; x.u=u; return x.f; }
DEV uint32_t asuint_(float f){ union{float f; uint32_t u;} x; x.f=f; return x.u; }
DEV unsigned short f2bf(float f){
  uint32_t u = asuint_(f);
  uint32_t r = (u + 0x7fffu + ((u>>16)&1u)) >> 16;
  return (unsigned short)r;
}
DEV float gelu_(float x){
  float x3 = x*x*x;
  float t  = 0.7978845608028654f * (x + 0.044715f*x3);
  float e  = __expf(2.0f*t);
  float th = 1.0f - 2.0f/(e + 1.0f);   // tanh(t), inf-safe
  return 0.5f * x * (1.0f + th);
}

#define GLL(gsrc, ldst) __builtin_amdgcn_global_load_lds( \
    (const __attribute__((address_space(1))) void*)(gsrc), \
    (__attribute__((address_space(3))) void*)(ldst), 16, 0, 0)

// ---------------- weight fp32 [K][N] -> bf16 W^T [N][K] ----------------
__global__ void wcvt_kernel(const float* __restrict__ W, unsigned short* __restrict__ WT,
                            int K, int N) {
  __shared__ float tile[32][33];
  int tx = threadIdx.x & 31, ty = threadIdx.x >> 5;       // 32 x 8
  int kb = blockIdx.x * 32, nb = blockIdx.y * 32;
  #pragma unroll
  for (int r = 0; r < 32; r += 8)
    tile[ty + r][tx] = W[(size_t)(kb + ty + r) * N + nb + tx];
  __syncthreads();
  #pragma unroll
  for (int r = 0; r < 32; r += 8)
    WT[(size_t)(nb + ty + r) * K + kb + tx] = f2bf(tile[tx][ty + r]);
}

// ---------------- layernorm fp32 -> bf16 ----------------
__global__ void ln_kernel(const float* __restrict__ X, const float* __restrict__ g,
                          const float* __restrict__ bb, unsigned short* __restrict__ O) {
  int row = blockIdx.x, t = threadIdx.x;
  const float4* xr = (const float4*)(X + (size_t)row * Cc);
  float4 v = xr[t];
  float s = v.x + v.y + v.z + v.w;
  float q = v.x*v.x + v.y*v.y + v.z*v.z + v.w*v.w;
  #pragma unroll
  for (int o = 32; o > 0; o >>= 1) { s += __shfl_xor(s, o); q += __shfl_xor(q, o); }
  __shared__ float ss[4], sq[4];
  int w = t >> 6;
  if ((t & 63) == 0) { ss[w] = s; sq[w] = q; }
  __syncthreads();
  s = ss[0] + ss[1] + ss[2] + ss[3];
  q = sq[0] + sq[1] + sq[2] + sq[3];
  float mu  = s * (1.0f/Cc);
  float var = q * (1.0f/Cc) - mu*mu;
  float rstd = rsqrtf(var + 1e-5f);
  float4 gv = ((const float4*)g)[t], bv = ((const float4*)bb)[t];
  ushort4 o4;
  o4.x = f2bf((v.x-mu)*rstd*gv.x + bv.x);
  o4.y = f2bf((v.y-mu)*rstd*gv.y + bv.y);
  o4.z = f2bf((v.z-mu)*rstd*gv.z + bv.z);
  o4.w = f2bf((v.w-mu)*rstd*gv.w + bv.w);
  ((ushort4*)(O + (size_t)row * Cc))[t] = o4;
}

// ---------------- GEMM: 128x128 tile, 8 waves (2x4), BK=64, swizzled LDS ----------
// MODE 0: +bias -> bf16 out        (qkv)
// MODE 2: +bias, gelu -> bf16      (fc1)
template<int MODE>
__launch_bounds__(512, 4)
__global__ void gemm_kernel(const unsigned short* __restrict__ A,
                            const unsigned short* __restrict__ BT,
                            const float* __restrict__ bias,
                            const float* __restrict__ res,
                            void* __restrict__ Cout,
                            int N, int K) {
  __shared__ unsigned short As[128*64];   // 16 KB, row-major [128][64], source pre-swizzled
  __shared__ unsigned short Bs[128*64];   // 16 KB
  int tid  = threadIdx.x;
  int lane = tid & 63, w = tid >> 6;
  int wr = w >> 2, wc = w & 3;            // wave tile: 64 (M) x 32 (N)
  int g = lane >> 4, ql = lane & 15;
  int bm = blockIdx.x, bn = blockIdx.y;

  f32x4 acc[4][2];
  #pragma unroll
  for (int m = 0; m < 4; ++m)
    #pragma unroll
    for (int n = 0; n < 2; ++n) acc[m][n] = (f32x4){0.f,0.f,0.f,0.f};

  int r  = tid >> 3;
  int cc = tid & 7;
  int sc = (cc ^ (r & 7)) * 8;
  const unsigned short* Ag = A  + (size_t)(bm*128 + r) * K + sc;
  const unsigned short* Bg = BT + (size_t)(bn*128 + r) * K + sc;
  int sw = (ql & 7) << 3;                 // fragment-read swizzle (shorts)
  int nk = K >> 6;

  for (int kt = 0; kt < nk; ++kt) {
    if (kt) __syncthreads();
    const unsigned short* ag = Ag + kt*64;
    const unsigned short* bg = Bg + kt*64;
    GLL(ag,                  As + w*512);
    GLL(ag + (size_t)64*K,   As + 4096 + w*512);
    GLL(bg,                  Bs + w*512);
    GLL(bg + (size_t)64*K,   Bs + 4096 + w*512);
    __syncthreads();

    #pragma unroll
    for (int kk = 0; kk < 2; ++kk) {
      int col = (kk*32 + g*8) ^ sw;
      bf16x8 af[4], bf2[2];
      #pragma unroll
      for (int m = 0; m < 4; ++m)
        af[m] = *(const bf16x8*)(As + (wr*64 + m*16 + ql)*64 + col);
      #pragma unroll
      for (int n = 0; n < 2; ++n)
        bf2[n] = *(const bf16x8*)(Bs + (wc*32 + n*16 + ql)*64 + col);
      #pragma unroll
      for (int m = 0; m < 4; ++m)
        #pragma unroll
        for (int n = 0; n < 2; ++n)
          acc[m][n] = __builtin_amdgcn_mfma_f32_16x16x32_bf16(af[m], bf2[n], acc[m][n], 0, 0, 0);
    }
  }

  int r0 = bm*128 + wr*64;
  int c0 = bn*128 + wc*32;
  int lr = g * 4;
  #pragma unroll
  for (int m = 0; m < 4; ++m) {
    #pragma unroll
    for (int n = 0; n < 2; ++n) {
      int col = c0 + n*16 + ql;
      float bv = bias[col];
      #pragma unroll
      for (int i = 0; i < 4; ++i) {
        int row = r0 + m*16 + lr + i;
        float v = acc[m][n][i] + bv;
        if (MODE == 2) v = gelu_(v);
        ((unsigned short*)Cout)[(size_t)row * N + col] = f2bf(v);
      }
    }
  }
}

// ---------------- split-K GEMM: 16 waves, two 8-wave K-halves, f32 out ---------
// C = A*(BT)^T + bias + res  (out-proj and fc2). Grid (M/128, N/128), block 1024.
// Waves 0-7: K[0,K/2); waves 8-15: K[K/2,K). Half-1 partials exchanged via the
// (dead) staging LDS with XOR-swizzled 16B chunks; half-0 adds + epilogue.
__launch_bounds__(1024, 2)
__global__ void gemm_skrf_kernel(const unsigned short* __restrict__ A,
                                 const unsigned short* __restrict__ BT,
                                 const float* __restrict__ bias,
                                 const float* __restrict__ res,
                                 float* __restrict__ Cout,
                                 int N, int K) {
  __shared__ __align__(16) unsigned short SMEM[32768];   // 64 KB
  // staging: AsH(wg) = SMEM + wg*8192, BsH(wg) = SMEM + 16384 + wg*8192
  int tid  = threadIdx.x;
  int lane = tid & 63, w = tid >> 6;
  int wg = w >> 3, w8 = w & 7;            // K-half, wave-in-half
  int wr = w8 >> 2, wc = w8 & 3;          // wave tile: 64 (M) x 32 (N)
  int g = lane >> 4, ql = lane & 15;
  int bm = blockIdx.x, bn = blockIdx.y;

  unsigned short* AsH = SMEM + wg*8192;
  unsigned short* BsH = SMEM + 16384 + wg*8192;

  f32x4 acc[4][2];
  #pragma unroll
  for (int m = 0; m < 4; ++m)
    #pragma unroll
    for (int n = 0; n < 2; ++n) acc[m][n] = (f32x4){0.f,0.f,0.f,0.f};

  int tid_h = tid & 511;
  int r  = tid_h >> 3;                    // 0..63 within half
  int cc = tid_h & 7;
  int sc = (cc ^ (r & 7)) * 8;
  int kbase = wg * (K >> 1);
  const unsigned short* Ag = A  + (size_t)(bm*128 + r) * K + kbase + sc;
  const unsigned short* Bg = BT + (size_t)(bn*128 + r) * K + kbase + sc;
  int sw = (ql & 7) << 3;
  int nk = K >> 7;                        // (K/2)/64 steps per half

  for (int kt = 0; kt < nk; ++kt) {
    if (kt) __syncthreads();
    const unsigned short* ag = Ag + kt*64;
    const unsigned short* bg = Bg + kt*64;
    GLL(ag,                  AsH + w8*512);
    GLL(ag + (size_t)64*K,   AsH + 4096 + w8*512);
    GLL(bg,                  BsH + w8*512);
    GLL(bg + (size_t)64*K,   BsH + 4096 + w8*512);
    __syncthreads();

    #pragma unroll
    for (int kk = 0; kk < 2; ++kk) {
      int col = (kk*32 + g*8) ^ sw;
      bf16x8 af[4], bf2[2];
      #pragma unroll
      for (int m = 0; m < 4; ++m)
        af[m] = *(const bf16x8*)(AsH + (wr*64 + m*16 + ql)*64 + col);
      #pragma unroll
      for (int n = 0; n < 2; ++n)
        bf2[n] = *(const bf16x8*)(BsH + (wc*32 + n*16 + ql)*64 + col);
      #pragma unroll
      for (int m = 0; m < 4; ++m)
        #pragma unroll
        for (int n = 0; n < 2; ++n)
          acc[m][n] = __builtin_amdgcn_mfma_f32_16x16x32_bf16(af[m], bf2[n], acc[m][n], 0, 0, 0);
    }
  }

  // ---- cross-half combine via LDS (staging area is dead now) ----
  __syncthreads();                        // all ds_reads of staging done
  float* ex = (float*)SMEM;               // 16384 floats = 64 KB
  int eb = (w8*64 + lane) * 32;
  if (wg == 1) {
    #pragma unroll
    for (int m = 0; m < 4; ++m)
      #pragma unroll
      for (int n = 0; n < 2; ++n) {
        int c = m*2 + n;
        *(f32x4*)&ex[eb + ((c ^ (lane & 7)) << 2)] = acc[m][n];
      }
  }
  __syncthreads();
  if (wg == 0) {
    #pragma unroll
    for (int m = 0; m < 4; ++m)
      #pragma unroll
      for (int n = 0; n < 2; ++n) {
        int c = m*2 + n;
        f32x4 o = *(const f32x4*)&ex[eb + ((c ^ (lane & 7)) << 2)];
        acc[m][n][0] += o[0]; acc[m][n][1] += o[1];
        acc[m][n][2] += o[2]; acc[m][n][3] += o[3];
      }
    int r0 = bm*128 + wr*64;
    int c0 = bn*128 + wc*32;
    int lr = g * 4;
    #pragma unroll
    for (int m = 0; m < 4; ++m) {
      #pragma unroll
      for (int n = 0; n < 2; ++n) {
        int col = c0 + n*16 + ql;
        float bv = bias[col];
        #pragma unroll
        for (int i = 0; i < 4; ++i) {
          int row = r0 + m*16 + lr + i;
          Cout[(size_t)row * N + col] = acc[m][n][i] + bv + res[(size_t)row * N + col];
        }
      }
    }
  }
}

// ---------------- V transpose: qkv V-third -> vtb[bh][64 d][2048 k] bf16 -------
__global__ void vtr_kernel(const unsigned short* __restrict__ qkv,
                           unsigned short* __restrict__ vtb) {
  __shared__ unsigned short Tl[64][72];
  int tid = threadIdx.x;
  int bh = blockIdx.x, tc = blockIdx.y;
  int b = bh >> 4, h = bh & 15;
  int r = tid >> 2, c0 = (tid & 3) * 16;
  const unsigned short* src = qkv + (size_t)(b*Tt + tc*64 + r)*3072 + 2048 + h*64 + c0;
  *(int4*)&Tl[r][c0]     = *(const int4*)(src);
  *(int4*)&Tl[r][c0 + 8] = *(const int4*)(src + 8);
  __syncthreads();
  int d = tid >> 2, k0 = (tid & 3) * 16;
  ushort4 o[4];
  #pragma unroll
  for (int jj = 0; jj < 4; ++jj) {
    o[jj].x = Tl[k0 + jj*4 + 0][d];
    o[jj].y = Tl[k0 + jj*4 + 1][d];
    o[jj].z = Tl[k0 + jj*4 + 2][d];
    o[jj].w = Tl[k0 + jj*4 + 3][d];
  }
  unsigned short* dst = vtb + ((size_t)(bh*64 + d))*2048 + tc*64 + k0;
  *(int4*)(dst)     = *(int4*)&o[0];
  *(int4*)(dst + 8) = *(int4*)&o[2];
}

// ---------------- MFMA flash attention (unchanged, passed refcheck) ----------------
__global__ __launch_bounds__(512, 4)
void attn_kernel(const unsigned short* __restrict__ qkv,
                 const unsigned short* __restrict__ vtb,
                 unsigned short* __restrict__ att) {
  __shared__ __align__(16) char smem[36864];   // K 8KB | VT 8KB | P 8x2560B
  int tid  = threadIdx.x;
  int lane = tid & 63, w = tid >> 6;
  int g = lane >> 4, ql = lane & 15;

  int bid = blockIdx.x;
  int bh = bid & 31;
  int jj = bid >> 5;
  int j  = (jj < 8) ? (2*jj) : (31 - 2*jj);    // pair long+short causal blocks
  int b = bh >> 4, h = bh & 15;
  int Q0 = j * 128;
  int qbase = Q0 + w * 16;
  char* Pb = smem + 16384 + w * 2560;          // per-wave P: [16 q][80 shorts]

  const unsigned short* qrow = qkv + (size_t)(b*Tt + qbase + ql) * 3072 + h*64;
  bf16x8 qf0 = *(const bf16x8*)(qrow + g*8);
  bf16x8 qf1 = *(const bf16x8*)(qrow + 32 + g*8);

  f32x4 O[4];
  #pragma unroll
  for (int d = 0; d < 4; ++d) O[d] = (f32x4){0.f,0.f,0.f,0.f};
  float mrun = -1e30f, lrun = 0.f;

  int nt = Q0/64 + 2;

  int srow = tid >> 3;
  int scol = (tid & 7) * 8;
  int wr_off = srow*128 + ((scol*2) ^ ((srow & 7) << 4));
  const unsigned short* Kg = qkv + (size_t)(b*Tt + srow)*3072 + 1024 + h*64 + scol;
  const unsigned short* Vg = vtb + ((size_t)(bh*64 + srow))*2048 + scol;

  int4 kreg = *(const int4*)(Kg);
  int4 vreg = *(const int4*)(Vg);

  for (int t0 = 0; t0 < nt; ++t0) {
    __syncthreads();                       // LDS free
    *(int4*)(smem + wr_off)        = kreg;
    *(int4*)(smem + 8192 + wr_off) = vreg;
    __syncthreads();                       // LDS ready
    if (t0 + 1 < nt) {
      kreg = *(const int4*)(Kg + (size_t)(t0+1)*64*3072);
      vreg = *(const int4*)(Vg + (t0+1)*64);
    }
    if (t0*64 > qbase + 15) continue;

    bool full = (t0*64 + 63) <= qbase;
    float ps[16];
    #pragma unroll
    for (int s = 0; s < 4; ++s) {
      int krow = s*16 + ql;
      int kb0 = krow*128 + (( g*16      ) ^ ((krow&7)<<4));
      int kb1 = krow*128 + (( g*16 + 64 ) ^ ((krow&7)<<4));
      bf16x8 kf0 = *(const bf16x8*)(smem + kb0);
      bf16x8 kf1 = *(const bf16x8*)(smem + kb1);
      f32x4 a = (f32x4){0.f,0.f,0.f,0.f};
      a = __builtin_amdgcn_mfma_f32_16x16x32_bf16(kf0, qf0, a, 0, 0, 0);
      a = __builtin_amdgcn_mfma_f32_16x16x32_bf16(kf1, qf1, a, 0, 0, 0);
      #pragma unroll
      for (int i = 0; i < 4; ++i) ps[s*4+i] = a[i] * 0.125f;
    }
    if (!full) {
      #pragma unroll
      for (int s = 0; s < 4; ++s)
        #pragma unroll
        for (int i = 0; i < 4; ++i)
          if (t0*64 + s*16 + g*4 + i > qbase + ql) ps[s*4+i] = -1e30f;
    }
    float tm = ps[0];
    #pragma unroll
    for (int i = 1; i < 16; ++i) tm = fmaxf(tm, ps[i]);
    tm = fmaxf(tm, __shfl_xor(tm, 16));
    tm = fmaxf(tm, __shfl_xor(tm, 32));
    float mnew = fmaxf(mrun, tm);
    float corr = __expf(mrun - mnew);
    float tsum = 0.f;
    #pragma unroll
    for (int s = 0; s < 4; ++s) {
      float e0 = __expf(ps[s*4+0] - mnew);
      float e1 = __expf(ps[s*4+1] - mnew);
      float e2 = __expf(ps[s*4+2] - mnew);
      float e3 = __expf(ps[s*4+3] - mnew);
      tsum += (e0 + e1) + (e2 + e3);
      ushort4 pk;
      pk.x = f2bf(e0); pk.y = f2bf(e1); pk.z = f2bf(e2); pk.w = f2bf(e3);
      *(ushort4*)(Pb + ql*160 + s*32 + g*8) = pk;
    }
    tsum += __shfl_xor(tsum, 16);
    tsum += __shfl_xor(tsum, 32);
    lrun = lrun * corr + tsum;
    mrun = mnew;

    float c0 = __shfl(corr, g*4 + 0);
    float c1 = __shfl(corr, g*4 + 1);
    float c2 = __shfl(corr, g*4 + 2);
    float c3 = __shfl(corr, g*4 + 3);
    #pragma unroll
    for (int d = 0; d < 4; ++d) {
      O[d][0] *= c0; O[d][1] *= c1; O[d][2] *= c2; O[d][3] *= c3;
    }
    #pragma unroll
    for (int kk = 0; kk < 2; ++kk) {
      bf16x8 pf = *(const bf16x8*)(Pb + ql*160 + kk*64 + g*16);
      #pragma unroll
      for (int d = 0; d < 4; ++d) {
        int drow = d*16 + ql;
        int vb = drow*128 + ((kk*64 + g*16) ^ ((drow&7)<<4));
        bf16x8 vf = *(const bf16x8*)(smem + 8192 + vb);
        O[d] = __builtin_amdgcn_mfma_f32_16x16x32_bf16(pf, vf, O[d], 0, 0, 0);
      }
    }
  }

  float l0 = __shfl(lrun, g*4 + 0);
  float l1 = __shfl(lrun, g*4 + 1);
  float l2 = __shfl(lrun, g*4 + 2);
  float l3 = __shfl(lrun, g*4 + 3);
  #pragma unroll
  for (int d = 0; d < 4; ++d) {
    size_t base = (size_t)(b*Tt + qbase)*Cc + h*64 + d*16 + ql;
    att[base + (size_t)(g*4+0)*Cc] = f2bf(O[d][0] / l0);
    att[base + (size_t)(g*4+1)*Cc] = f2bf(O[d][1] / l1);
    att[base + (size_t)(g*4+2)*Cc] = f2bf(O[d][2] / l2);
    att[base + (size_t)(g*4+3)*Cc] = f2bf(O[d][3] / l3);
  }
}

// ---------------- launch ----------------
extern "C" void kernel_launch(void* const* d_in, const int* in_sizes, int n_in,
                              void* d_out, int out_size, void* d_ws, size_t ws_size,
                              hipStream_t stream) {
  const float* x    = (const float*)d_in[0];
  const float* ln1g = (const float*)d_in[1];
  const float* ln1b = (const float*)d_in[2];
  const float* Wqkv = (const float*)d_in[3];
  const float* bqkv = (const float*)d_in[4];
  const float* Wout = (const float*)d_in[5];
  const float* bout = (const float*)d_in[6];
  const float* ln2g = (const float*)d_in[7];
  const float* ln2b = (const float*)d_in[8];
  const float* Wfc1 = (const float*)d_in[9];
  const float* bfc1 = (const float*)d_in[10];
  const float* Wfc2 = (const float*)d_in[11];
  const float* bfc2 = (const float*)d_in[12];

  char* ws = (char*)d_ws;
  unsigned short* wqkvT = (unsigned short*)(ws);                 // 6 MB  [3072][1024]
  unsigned short* woutT = (unsigned short*)(ws + (6u<<20));      // 2 MB  [1024][1024]
  unsigned short* wfc1T = (unsigned short*)(ws + (8u<<20));      // 8 MB  [4096][1024]
  unsigned short* wfc2T = (unsigned short*)(ws + (16u<<20));     // 8 MB  [1024][4096]
  unsigned short* vtb   = (unsigned short*)(ws + (24u<<20));     // 8 MB  (dead before temp written)
  float*          temp  = (float*)(ws + (24u<<20));              // 16 MB [4096][1024] (after attn)
  unsigned short* hbuf  = (unsigned short*)(ws + (40u<<20));     // 8 MB  [4096][1024]
  unsigned short* qkvb  = (unsigned short*)(ws + (48u<<20));     // 24 MB [4096][3072]
  unsigned short* attb  = (unsigned short*)(ws + (72u<<20));     // 8 MB  [4096][1024]
  unsigned short* a1b   = (unsigned short*)(ws + (48u<<20));     // 32 MB (reuses qkv+att)

  dim3 b256(256), b512(512), b1024(1024);
  wcvt_kernel<<<dim3(1024/32, 3072/32), b256, 0, stream>>>(Wqkv, wqkvT, 1024, 3072);
  wcvt_kernel<<<dim3(1024/32, 1024/32), b256, 0, stream>>>(Wout, woutT, 1024, 1024);
  wcvt_kernel<<<dim3(1024/32, 4096/32), b256, 0, stream>>>(Wfc1, wfc1T, 1024, 4096);
  wcvt_kernel<<<dim3(4096/32, 1024/32), b256, 0, stream>>>(Wfc2, wfc2T, 4096, 1024);

  ln_kernel<<<Mm, b256, 0, stream>>>(x, ln1g, ln1b, hbuf);
  gemm_kernel<0><<<dim3(Mm/128, 3072/128), b512, 0, stream>>>(hbuf, wqkvT, bqkv, nullptr, qkvb, 3072, 1024);
  vtr_kernel<<<dim3(32, 32), b256, 0, stream>>>(qkvb, vtb);
  attn_kernel<<<dim3(512), 512, 0, stream>>>(qkvb, vtb, attb);
  gemm_skrf_kernel<<<dim3(Mm/128, 1024/128), b1024, 0, stream>>>(attb, woutT, bout, x, temp, 1024, 1024);
  ln_kernel<<<Mm, b256, 0, stream>>>(temp, ln2g, ln2b, hbuf);
  gemm_kernel<2><<<dim3(Mm/128, 4096/128), b512, 0, stream>>>(hbuf, wfc1T, bfc1, nullptr, a1b, 4096, 1024);
  gemm_skrf_kernel<<<dim3(Mm/128, 1024/128), b1024, 0, stream>>>(a1b, wfc2T, bfc2, temp, (float*)d_out, 1024, 4096);
}

// Round 7
// 323.390 us; speedup vs baseline: 4.0540x; 1.1010x over previous
//
#include <hip/hip_runtime.h>
#include <stdint.h>

// ---------------- constants ----------------
#define Bb 2
#define Tt 2048
#define Cc 1024
#define Hh 16
#define HD 64
#define Mm (Bb*Tt)   // 4096

typedef __bf16 bf16x8 __attribute__((ext_vector_type(8)));
typedef float  f32x4  __attribute__((ext_vector_type(4)));

#define DEV static __device__ __forceinline__

DEV float asfloat_(uint32_t u){ union{uint32_t u; float f;} x; x.u=u; return x.f; }
DEV uint32_t asuint_(float f){ union{float f; uint32_t u;} x; x.f=f; return x.u; }
DEV unsigned short f2bf(float f){
  uint32_t u = asuint_(f);
  uint32_t r = (u + 0x7fffu + ((u>>16)&1u)) >> 16;
  return (unsigned short)r;
}
DEV float gelu_(float x){
  float x3 = x*x*x;
  float t  = 0.7978845608028654f * (x + 0.044715f*x3);
  float e  = __expf(2.0f*t);
  float th = 1.0f - 2.0f/(e + 1.0f);   // tanh(t), inf-safe
  return 0.5f * x * (1.0f + th);
}

#define GLL(gsrc, ldst) __builtin_amdgcn_global_load_lds( \
    (const __attribute__((address_space(1))) void*)(gsrc), \
    (__attribute__((address_space(3))) void*)(ldst), 16, 0, 0)

// ---------------- weight fp32 [K][N] -> bf16 W^T [N][K] ----------------
__global__ void wcvt_kernel(const float* __restrict__ W, unsigned short* __restrict__ WT,
                            int K, int N) {
  __shared__ float tile[32][33];
  int tx = threadIdx.x & 31, ty = threadIdx.x >> 5;       // 32 x 8
  int kb = blockIdx.x * 32, nb = blockIdx.y * 32;
  #pragma unroll
  for (int r = 0; r < 32; r += 8)
    tile[ty + r][tx] = W[(size_t)(kb + ty + r) * N + nb + tx];
  __syncthreads();
  #pragma unroll
  for (int r = 0; r < 32; r += 8)
    WT[(size_t)(nb + ty + r) * K + kb + tx] = f2bf(tile[tx][ty + r]);
}

// ---------------- layernorm fp32 -> bf16 ----------------
__global__ void ln_kernel(const float* __restrict__ X, const float* __restrict__ g,
                          const float* __restrict__ bb, unsigned short* __restrict__ O) {
  int row = blockIdx.x, t = threadIdx.x;
  const float4* xr = (const float4*)(X + (size_t)row * Cc);
  float4 v = xr[t];
  float s = v.x + v.y + v.z + v.w;
  float q = v.x*v.x + v.y*v.y + v.z*v.z + v.w*v.w;
  #pragma unroll
  for (int o = 32; o > 0; o >>= 1) { s += __shfl_xor(s, o); q += __shfl_xor(q, o); }
  __shared__ float ss[4], sq[4];
  int w = t >> 6;
  if ((t & 63) == 0) { ss[w] = s; sq[w] = q; }
  __syncthreads();
  s = ss[0] + ss[1] + ss[2] + ss[3];
  q = sq[0] + sq[1] + sq[2] + sq[3];
  float mu  = s * (1.0f/Cc);
  float var = q * (1.0f/Cc) - mu*mu;
  float rstd = rsqrtf(var + 1e-5f);
  float4 gv = ((const float4*)g)[t], bv = ((const float4*)bb)[t];
  ushort4 o4;
  o4.x = f2bf((v.x-mu)*rstd*gv.x + bv.x);
  o4.y = f2bf((v.y-mu)*rstd*gv.y + bv.y);
  o4.z = f2bf((v.z-mu)*rstd*gv.z + bv.z);
  o4.w = f2bf((v.w-mu)*rstd*gv.w + bv.w);
  ((ushort4*)(O + (size_t)row * Cc))[t] = o4;
}

// ---------------- GEMM: 128x128 tile, 8 waves (2x4), BK=64, 2-phase dbuf ----------
// MODE 0: +bias -> bf16 out        (qkv)
// MODE 2: +bias, gelu -> bf16      (fc1)
template<int MODE>
__launch_bounds__(512, 4)
__global__ void gemm_kernel(const unsigned short* __restrict__ A,
                            const unsigned short* __restrict__ BT,
                            const float* __restrict__ bias,
                            const float* __restrict__ res,
                            void* __restrict__ Cout,
                            int N, int K) {
  __shared__ unsigned short As[2][128*64];   // 2 x 16 KB, source pre-swizzled
  __shared__ unsigned short Bs[2][128*64];   // 2 x 16 KB
  int tid  = threadIdx.x;
  int lane = tid & 63, w = tid >> 6;
  int wr = w >> 2, wc = w & 3;            // wave tile: 64 (M) x 32 (N)
  int g = lane >> 4, ql = lane & 15;
  int bm = blockIdx.x, bn = blockIdx.y;

  f32x4 acc[4][2];
  #pragma unroll
  for (int m = 0; m < 4; ++m)
    #pragma unroll
    for (int n = 0; n < 2; ++n) acc[m][n] = (f32x4){0.f,0.f,0.f,0.f};

  int r  = tid >> 3;
  int cc = tid & 7;
  int sc = (cc ^ (r & 7)) * 8;
  const unsigned short* Ag = A  + (size_t)(bm*128 + r) * K + sc;
  const unsigned short* Bg = BT + (size_t)(bn*128 + r) * K + sc;
  int sw = (ql & 7) << 3;                 // fragment-read swizzle (shorts)
  int nk = K >> 6;

  // prologue: stage tile 0 into buffer 0
  GLL(Ag,                 As[0] + w*512);
  GLL(Ag + (size_t)64*K,  As[0] + 4096 + w*512);
  GLL(Bg,                 Bs[0] + w*512);
  GLL(Bg + (size_t)64*K,  Bs[0] + 4096 + w*512);
  __syncthreads();

  int cur = 0;
  for (int kt = 0; kt < nk; ++kt) {
    if (kt + 1 < nk) {                    // issue next-tile loads (overlap compute)
      const unsigned short* ag = Ag + (kt+1)*64;
      const unsigned short* bg = Bg + (kt+1)*64;
      GLL(ag,                 As[cur^1] + w*512);
      GLL(ag + (size_t)64*K,  As[cur^1] + 4096 + w*512);
      GLL(bg,                 Bs[cur^1] + w*512);
      GLL(bg + (size_t)64*K,  Bs[cur^1] + 4096 + w*512);
    }
    const unsigned short* Asc = As[cur];
    const unsigned short* Bsc = Bs[cur];
    #pragma unroll
    for (int kk = 0; kk < 2; ++kk) {
      int col = (kk*32 + g*8) ^ sw;
      bf16x8 af[4], bf2[2];
      #pragma unroll
      for (int m = 0; m < 4; ++m)
        af[m] = *(const bf16x8*)(Asc + (wr*64 + m*16 + ql)*64 + col);
      #pragma unroll
      for (int n = 0; n < 2; ++n)
        bf2[n] = *(const bf16x8*)(Bsc + (wc*32 + n*16 + ql)*64 + col);
      #pragma unroll
      for (int m = 0; m < 4; ++m)
        #pragma unroll
        for (int n = 0; n < 2; ++n)
          acc[m][n] = __builtin_amdgcn_mfma_f32_16x16x32_bf16(af[m], bf2[n], acc[m][n], 0, 0, 0);
    }
    __syncthreads();                      // drains the prefetch GLLs (post-compute)
    cur ^= 1;
  }

  int r0 = bm*128 + wr*64;
  int c0 = bn*128 + wc*32;
  int lr = g * 4;
  #pragma unroll
  for (int m = 0; m < 4; ++m) {
    #pragma unroll
    for (int n = 0; n < 2; ++n) {
      int col = c0 + n*16 + ql;
      float bv = bias[col];
      #pragma unroll
      for (int i = 0; i < 4; ++i) {
        int row = r0 + m*16 + lr + i;
        float v = acc[m][n][i] + bv;
        if (MODE == 2) v = gelu_(v);
        ((unsigned short*)Cout)[(size_t)row * N + col] = f2bf(v);
      }
    }
  }
}

// ---------------- split-K GEMM: 16 waves, two 8-wave K-halves, 2-phase dbuf ---------
// C = A*(BT)^T + bias + res  (out-proj and fc2). Grid (M/128, N/128), block 1024.
// Waves 0-7: K[0,K/2); waves 8-15: K[K/2,K). Half-1 partials exchanged via the
// (dead) staging LDS with XOR-swizzled 16B chunks; half-0 adds + epilogue.
__launch_bounds__(1024, 2)
__global__ void gemm_skrf_kernel(const unsigned short* __restrict__ A,
                                 const unsigned short* __restrict__ BT,
                                 const float* __restrict__ bias,
                                 const float* __restrict__ res,
                                 float* __restrict__ Cout,
                                 int N, int K) {
  __shared__ __align__(16) unsigned short SMEM[2][32768];   // 2 x 64 KB
  // within a buffer: AsH(wg) = + wg*8192, BsH(wg) = + 16384 + wg*8192
  int tid  = threadIdx.x;
  int lane = tid & 63, w = tid >> 6;
  int wg = w >> 3, w8 = w & 7;            // K-half, wave-in-half
  int wr = w8 >> 2, wc = w8 & 3;          // wave tile: 64 (M) x 32 (N)
  int g = lane >> 4, ql = lane & 15;
  int bm = blockIdx.x, bn = blockIdx.y;

  f32x4 acc[4][2];
  #pragma unroll
  for (int m = 0; m < 4; ++m)
    #pragma unroll
    for (int n = 0; n < 2; ++n) acc[m][n] = (f32x4){0.f,0.f,0.f,0.f};

  int tid_h = tid & 511;
  int r  = tid_h >> 3;                    // 0..63 within half
  int cc = tid_h & 7;
  int sc = (cc ^ (r & 7)) * 8;
  int kbase = wg * (K >> 1);
  const unsigned short* Ag = A  + (size_t)(bm*128 + r) * K + kbase + sc;
  const unsigned short* Bg = BT + (size_t)(bn*128 + r) * K + kbase + sc;
  int sw = (ql & 7) << 3;
  int nk = K >> 7;                        // (K/2)/64 steps per half

  // prologue: stage tile 0 into buffer 0
  GLL(Ag,                 SMEM[0] + wg*8192 + w8*512);
  GLL(Ag + (size_t)64*K,  SMEM[0] + wg*8192 + 4096 + w8*512);
  GLL(Bg,                 SMEM[0] + 16384 + wg*8192 + w8*512);
  GLL(Bg + (size_t)64*K,  SMEM[0] + 16384 + wg*8192 + 4096 + w8*512);
  __syncthreads();

  int cur = 0;
  for (int kt = 0; kt < nk; ++kt) {
    if (kt + 1 < nk) {
      const unsigned short* ag = Ag + (kt+1)*64;
      const unsigned short* bg = Bg + (kt+1)*64;
      unsigned short* nb = SMEM[cur^1];
      GLL(ag,                 nb + wg*8192 + w8*512);
      GLL(ag + (size_t)64*K,  nb + wg*8192 + 4096 + w8*512);
      GLL(bg,                 nb + 16384 + wg*8192 + w8*512);
      GLL(bg + (size_t)64*K,  nb + 16384 + wg*8192 + 4096 + w8*512);
    }
    const unsigned short* AsH = SMEM[cur] + wg*8192;
    const unsigned short* BsH = SMEM[cur] + 16384 + wg*8192;
    #pragma unroll
    for (int kk = 0; kk < 2; ++kk) {
      int col = (kk*32 + g*8) ^ sw;
      bf16x8 af[4], bf2[2];
      #pragma unroll
      for (int m = 0; m < 4; ++m)
        af[m] = *(const bf16x8*)(AsH + (wr*64 + m*16 + ql)*64 + col);
      #pragma unroll
      for (int n = 0; n < 2; ++n)
        bf2[n] = *(const bf16x8*)(BsH + (wc*32 + n*16 + ql)*64 + col);
      #pragma unroll
      for (int m = 0; m < 4; ++m)
        #pragma unroll
        for (int n = 0; n < 2; ++n)
          acc[m][n] = __builtin_amdgcn_mfma_f32_16x16x32_bf16(af[m], bf2[n], acc[m][n], 0, 0, 0);
    }
    __syncthreads();
    cur ^= 1;
  }

  // ---- cross-half combine via LDS (staging buffer 0 is dead now) ----
  float* ex = (float*)SMEM[0];            // 16384 floats = 64 KB
  int eb = (w8*64 + lane) * 32;
  if (wg == 1) {
    #pragma unroll
    for (int m = 0; m < 4; ++m)
      #pragma unroll
      for (int n = 0; n < 2; ++n) {
        int c = m*2 + n;
        *(f32x4*)&ex[eb + ((c ^ (lane & 7)) << 2)] = acc[m][n];
      }
  }
  __syncthreads();
  if (wg == 0) {
    #pragma unroll
    for (int m = 0; m < 4; ++m)
      #pragma unroll
      for (int n = 0; n < 2; ++n) {
        int c = m*2 + n;
        f32x4 o = *(const f32x4*)&ex[eb + ((c ^ (lane & 7)) << 2)];
        acc[m][n][0] += o[0]; acc[m][n][1] += o[1];
        acc[m][n][2] += o[2]; acc[m][n][3] += o[3];
      }
    int r0 = bm*128 + wr*64;
    int c0 = bn*128 + wc*32;
    int lr = g * 4;
    #pragma unroll
    for (int m = 0; m < 4; ++m) {
      #pragma unroll
      for (int n = 0; n < 2; ++n) {
        int col = c0 + n*16 + ql;
        float bv = bias[col];
        #pragma unroll
        for (int i = 0; i < 4; ++i) {
          int row = r0 + m*16 + lr + i;
          Cout[(size_t)row * N + col] = acc[m][n][i] + bv + res[(size_t)row * N + col];
        }
      }
    }
  }
}

// ---------------- V transpose: qkv V-third -> vtb[bh][64 d][2048 k] bf16 -------
__global__ void vtr_kernel(const unsigned short* __restrict__ qkv,
                           unsigned short* __restrict__ vtb) {
  __shared__ unsigned short Tl[64][72];
  int tid = threadIdx.x;
  int bh = blockIdx.x, tc = blockIdx.y;
  int b = bh >> 4, h = bh & 15;
  int r = tid >> 2, c0 = (tid & 3) * 16;
  const unsigned short* src = qkv + (size_t)(b*Tt + tc*64 + r)*3072 + 2048 + h*64 + c0;
  *(int4*)&Tl[r][c0]     = *(const int4*)(src);
  *(int4*)&Tl[r][c0 + 8] = *(const int4*)(src + 8);
  __syncthreads();
  int d = tid >> 2, k0 = (tid & 3) * 16;
  ushort4 o[4];
  #pragma unroll
  for (int jj = 0; jj < 4; ++jj) {
    o[jj].x = Tl[k0 + jj*4 + 0][d];
    o[jj].y = Tl[k0 + jj*4 + 1][d];
    o[jj].z = Tl[k0 + jj*4 + 2][d];
    o[jj].w = Tl[k0 + jj*4 + 3][d];
  }
  unsigned short* dst = vtb + ((size_t)(bh*64 + d))*2048 + tc*64 + k0;
  *(int4*)(dst)     = *(int4*)&o[0];
  *(int4*)(dst + 8) = *(int4*)&o[2];
}

// ---------------- MFMA flash attention (unchanged, passed refcheck) ----------------
__global__ __launch_bounds__(512, 4)
void attn_kernel(const unsigned short* __restrict__ qkv,
                 const unsigned short* __restrict__ vtb,
                 unsigned short* __restrict__ att) {
  __shared__ __align__(16) char smem[36864];   // K 8KB | VT 8KB | P 8x2560B
  int tid  = threadIdx.x;
  int lane = tid & 63, w = tid >> 6;
  int g = lane >> 4, ql = lane & 15;

  int bid = blockIdx.x;
  int bh = bid & 31;
  int jj = bid >> 5;
  int j  = (jj < 8) ? (2*jj) : (31 - 2*jj);    // pair long+short causal blocks
  int b = bh >> 4, h = bh & 15;
  int Q0 = j * 128;
  int qbase = Q0 + w * 16;
  char* Pb = smem + 16384 + w * 2560;          // per-wave P: [16 q][80 shorts]

  const unsigned short* qrow = qkv + (size_t)(b*Tt + qbase + ql) * 3072 + h*64;
  bf16x8 qf0 = *(const bf16x8*)(qrow + g*8);
  bf16x8 qf1 = *(const bf16x8*)(qrow + 32 + g*8);

  f32x4 O[4];
  #pragma unroll
  for (int d = 0; d < 4; ++d) O[d] = (f32x4){0.f,0.f,0.f,0.f};
  float mrun = -1e30f, lrun = 0.f;

  int nt = Q0/64 + 2;

  int srow = tid >> 3;
  int scol = (tid & 7) * 8;
  int wr_off = srow*128 + ((scol*2) ^ ((srow & 7) << 4));
  const unsigned short* Kg = qkv + (size_t)(b*Tt + srow)*3072 + 1024 + h*64 + scol;
  const unsigned short* Vg = vtb + ((size_t)(bh*64 + srow))*2048 + scol;

  int4 kreg = *(const int4*)(Kg);
  int4 vreg = *(const int4*)(Vg);

  for (int t0 = 0; t0 < nt; ++t0) {
    __syncthreads();                       // LDS free
    *(int4*)(smem + wr_off)        = kreg;
    *(int4*)(smem + 8192 + wr_off) = vreg;
    __syncthreads();                       // LDS ready
    if (t0 + 1 < nt) {
      kreg = *(const int4*)(Kg + (size_t)(t0+1)*64*3072);
      vreg = *(const int4*)(Vg + (t0+1)*64);
    }
    if (t0*64 > qbase + 15) continue;

    bool full = (t0*64 + 63) <= qbase;
    float ps[16];
    #pragma unroll
    for (int s = 0; s < 4; ++s) {
      int krow = s*16 + ql;
      int kb0 = krow*128 + (( g*16      ) ^ ((krow&7)<<4));
      int kb1 = krow*128 + (( g*16 + 64 ) ^ ((krow&7)<<4));
      bf16x8 kf0 = *(const bf16x8*)(smem + kb0);
      bf16x8 kf1 = *(const bf16x8*)(smem + kb1);
      f32x4 a = (f32x4){0.f,0.f,0.f,0.f};
      a = __builtin_amdgcn_mfma_f32_16x16x32_bf16(kf0, qf0, a, 0, 0, 0);
      a = __builtin_amdgcn_mfma_f32_16x16x32_bf16(kf1, qf1, a, 0, 0, 0);
      #pragma unroll
      for (int i = 0; i < 4; ++i) ps[s*4+i] = a[i] * 0.125f;
    }
    if (!full) {
      #pragma unroll
      for (int s = 0; s < 4; ++s)
        #pragma unroll
        for (int i = 0; i < 4; ++i)
          if (t0*64 + s*16 + g*4 + i > qbase + ql) ps[s*4+i] = -1e30f;
    }
    float tm = ps[0];
    #pragma unroll
    for (int i = 1; i < 16; ++i) tm = fmaxf(tm, ps[i]);
    tm = fmaxf(tm, __shfl_xor(tm, 16));
    tm = fmaxf(tm, __shfl_xor(tm, 32));
    float mnew = fmaxf(mrun, tm);
    float corr = __expf(mrun - mnew);
    float tsum = 0.f;
    #pragma unroll
    for (int s = 0; s < 4; ++s) {
      float e0 = __expf(ps[s*4+0] - mnew);
      float e1 = __expf(ps[s*4+1] - mnew);
      float e2 = __expf(ps[s*4+2] - mnew);
      float e3 = __expf(ps[s*4+3] - mnew);
      tsum += (e0 + e1) + (e2 + e3);
      ushort4 pk;
      pk.x = f2bf(e0); pk.y = f2bf(e1); pk.z = f2bf(e2); pk.w = f2bf(e3);
      *(ushort4*)(Pb + ql*160 + s*32 + g*8) = pk;
    }
    tsum += __shfl_xor(tsum, 16);
    tsum += __shfl_xor(tsum, 32);
    lrun = lrun * corr + tsum;
    mrun = mnew;

    float c0 = __shfl(corr, g*4 + 0);
    float c1 = __shfl(corr, g*4 + 1);
    float c2 = __shfl(corr, g*4 + 2);
    float c3 = __shfl(corr, g*4 + 3);
    #pragma unroll
    for (int d = 0; d < 4; ++d) {
      O[d][0] *= c0; O[d][1] *= c1; O[d][2] *= c2; O[d][3] *= c3;
    }
    #pragma unroll
    for (int kk = 0; kk < 2; ++kk) {
      bf16x8 pf = *(const bf16x8*)(Pb + ql*160 + kk*64 + g*16);
      #pragma unroll
      for (int d = 0; d < 4; ++d) {
        int drow = d*16 + ql;
        int vb = drow*128 + ((kk*64 + g*16) ^ ((drow&7)<<4));
        bf16x8 vf = *(const bf16x8*)(smem + 8192 + vb);
        O[d] = __builtin_amdgcn_mfma_f32_16x16x32_bf16(pf, vf, O[d], 0, 0, 0);
      }
    }
  }

  float l0 = __shfl(lrun, g*4 + 0);
  float l1 = __shfl(lrun, g*4 + 1);
  float l2 = __shfl(lrun, g*4 + 2);
  float l3 = __shfl(lrun, g*4 + 3);
  #pragma unroll
  for (int d = 0; d < 4; ++d) {
    size_t base = (size_t)(b*Tt + qbase)*Cc + h*64 + d*16 + ql;
    att[base + (size_t)(g*4+0)*Cc] = f2bf(O[d][0] / l0);
    att[base + (size_t)(g*4+1)*Cc] = f2bf(O[d][1] / l1);
    att[base + (size_t)(g*4+2)*Cc] = f2bf(O[d][2] / l2);
    att[base + (size_t)(g*4+3)*Cc] = f2bf(O[d][3] / l3);
  }
}

// ---------------- launch ----------------
extern "C" void kernel_launch(void* const* d_in, const int* in_sizes, int n_in,
                              void* d_out, int out_size, void* d_ws, size_t ws_size,
                              hipStream_t stream) {
  const float* x    = (const float*)d_in[0];
  const float* ln1g = (const float*)d_in[1];
  const float* ln1b = (const float*)d_in[2];
  const float* Wqkv = (const float*)d_in[3];
  const float* bqkv = (const float*)d_in[4];
  const float* Wout = (const float*)d_in[5];
  const float* bout = (const float*)d_in[6];
  const float* ln2g = (const float*)d_in[7];
  const float* ln2b = (const float*)d_in[8];
  const float* Wfc1 = (const float*)d_in[9];
  const float* bfc1 = (const float*)d_in[10];
  const float* Wfc2 = (const float*)d_in[11];
  const float* bfc2 = (const float*)d_in[12];

  char* ws = (char*)d_ws;
  unsigned short* wqkvT = (unsigned short*)(ws);                 // 6 MB  [3072][1024]
  unsigned short* woutT = (unsigned short*)(ws + (6u<<20));      // 2 MB  [1024][1024]
  unsigned short* wfc1T = (unsigned short*)(ws + (8u<<20));      // 8 MB  [4096][1024]
  unsigned short* wfc2T = (unsigned short*)(ws + (16u<<20));     // 8 MB  [1024][4096]
  unsigned short* vtb   = (unsigned short*)(ws + (24u<<20));     // 8 MB  (dead before temp written)
  float*          temp  = (float*)(ws + (24u<<20));              // 16 MB [4096][1024] (after attn)
  unsigned short* hbuf  = (unsigned short*)(ws + (40u<<20));     // 8 MB  [4096][1024]
  unsigned short* qkvb  = (unsigned short*)(ws + (48u<<20));     // 24 MB [4096][3072]
  unsigned short* attb  = (unsigned short*)(ws + (72u<<20));     // 8 MB  [4096][1024]
  unsigned short* a1b   = (unsigned short*)(ws + (48u<<20));     // 32 MB (reuses qkv+att)

  dim3 b256(256), b512(512), b1024(1024);
  wcvt_kernel<<<dim3(1024/32, 3072/32), b256, 0, stream>>>(Wqkv, wqkvT, 1024, 3072);
  wcvt_kernel<<<dim3(1024/32, 1024/32), b256, 0, stream>>>(Wout, woutT, 1024, 1024);
  wcvt_kernel<<<dim3(1024/32, 4096/32), b256, 0, stream>>>(Wfc1, wfc1T, 1024, 4096);
  wcvt_kernel<<<dim3(4096/32, 1024/32), b256, 0, stream>>>(Wfc2, wfc2T, 4096, 1024);

  ln_kernel<<<Mm, b256, 0, stream>>>(x, ln1g, ln1b, hbuf);
  gemm_kernel<0><<<dim3(Mm/128, 3072/128), b512, 0, stream>>>(hbuf, wqkvT, bqkv, nullptr, qkvb, 3072, 1024);
  vtr_kernel<<<dim3(32, 32), b256, 0, stream>>>(qkvb, vtb);
  attn_kernel<<<dim3(512), 512, 0, stream>>>(qkvb, vtb, attb);
  gemm_skrf_kernel<<<dim3(Mm/128, 1024/128), b1024, 0, stream>>>(attb, woutT, bout, x, temp, 1024, 1024);
  ln_kernel<<<Mm, b256, 0, stream>>>(temp, ln2g, ln2b, hbuf);
  gemm_kernel<2><<<dim3(Mm/128, 4096/128), b512, 0, stream>>>(hbuf, wfc1T, bfc1, nullptr, a1b, 4096, 1024);
  gemm_skrf_kernel<<<dim3(Mm/128, 1024/128), b1024, 0, stream>>>(a1b, wfc2T, bfc2, temp, (float*)d_out, 1024, 4096);
}